// Round 9
// baseline (613.916 us; speedup 1.0000x reference)
//
#include <hip/hip_runtime.h>

typedef unsigned int u32;
typedef unsigned short u16;
typedef __attribute__((ext_vector_type(8))) short short8;   // 8 bf16 (4 VGPRs)
typedef __attribute__((ext_vector_type(4))) float f32x4;
typedef __attribute__((ext_vector_type(2))) float f32x2;

#define DEV __device__ __forceinline__
#define LOG2E 1.44269504089f

DEV u16 f2bf(float f) {
    u32 u = __float_as_uint(f);
    return (u16)((u + 0x7FFFu + ((u >> 16) & 1u)) >> 16);
}
DEV float bf2f(u16 h) { return __uint_as_float(((u32)h) << 16); }
DEV float frcp(float x) { return __builtin_amdgcn_rcpf(x); }
DEV float fexp2(float x) {
#if __has_builtin(__builtin_amdgcn_exp2f)
    return __builtin_amdgcn_exp2f(x);
#else
    return exp2f(x);
#endif
}
DEV u32 pack_bf16(float a, float b) {
#if __has_builtin(__builtin_amdgcn_cvt_pk_bf16_f32)
    auto v = __builtin_amdgcn_cvt_pk_bf16_f32(a, b);   // lo=a, hi=b
    u32 r; __builtin_memcpy(&r, &v, 4); return r;
#else
    return (u32)f2bf(a) | ((u32)f2bf(b) << 16);
#endif
}
// extract r-th bf16 (r constant under unroll) from packed uint2
DEV float xex(uint2 v, int r) {
    u32 u = (r & 2) ? v.y : v.x;
    return (r & 1) ? __uint_as_float(u & 0xFFFF0000u) : __uint_as_float(u << 16);
}

// Gate-row permutation (R13-proven): new row g' (bit layout [mi:2][w:3][rg:2][r:2])
// maps to old gate = type r, channel 16w+4rg+mi.  Each thread's 4 acc elements
// of ONE tile are {zi,zf,zg,zo} of ONE channel; channels stay the contiguous
// quad chb..chb+3.  Applied to weight rows + biases in both producer+consumer.
DEV int gmap2(int g) { return ((g & 3) << 7) + (g & 0x7C) + (g >> 7); }

// packed-pair helpers
DEV f32x2 exp2p(f32x2 a) { f32x2 r; r.x = fexp2(a.x); r.y = fexp2(a.y); return r; }
DEV f32x2 rcpp(f32x2 a)  { f32x2 r; r.x = frcp(a.x);  r.y = frcp(a.y);  return r; }
DEV f32x2 minp(f32x2 a, float b) { f32x2 r; r.x = fminf(a.x, b); r.y = fminf(a.y, b); return r; }

// one LSTM elementwise step on a PAIR of channels (proven op order)
DEV f32x2 lstm_pair(f32x2 zi, f32x2 zf, f32x2 zg, f32x2 zo, f32x2* cst) {
    f32x2 ei = exp2p(-zi);
    f32x2 ef = exp2p(-zf);
    f32x2 eo = exp2p(-zo);
    f32x2 eg = exp2p(minp(zg + zg, 115.f));
    f32x2 A = 1.f + ei, F = 1.f + ef, G = eg + 1.f, O = 1.f + eo;
    f32x2 AG = A * G;
    f32x2 cc = (*cst * AG + (eg - 1.f) * F) * rcpp(F * AG);
    *cst = cc;
    f32x2 ec = exp2p(minp(cc * 2.885390082f, 115.f));
    return (ec - 1.f) * rcpp(O * (ec + 1.f));
}

// ---------------------------------------------------------------------------
// K_FUSED (R16): producer-consumer fusion of inproj2 + lstm.
//   blocks 0..7    : LSTM consumers (R13 body; 8 waves, gmap2 tiling).
//   blocks 8..519  : X producers (R15 2-step inproj body), chunk c = blk-8.
// Sync: flags[d*32 + (s/16)] counts producer blocks done for that 16-step
// super-chunk (8 each).  Producer: stores -> __syncthreads (vmcnt drain) ->
// release fetch_add.  Consumer: acquire poll before prefetch crosses into a
// new super-chunk (every 8 iters).  One-way dependency => deadlock-free.
// Flags live in the feats buffer (zeroed by memset node each replay;
// overwritten later by k_feats).  X values & LSTM math bit-identical to R13.
// ---------------------------------------------------------------------------
__global__ __launch_bounds__(512) void k_fused(
    const int* __restrict__ sent, const float* __restrict__ emb,
    const float* __restrict__ wihf, const float* __restrict__ bihf, const float* __restrict__ bhhf,
    const float* __restrict__ wihb, const float* __restrict__ bihb, const float* __restrict__ bhhb,
    u16* __restrict__ Xf, u16* __restrict__ Xb,
    const float* __restrict__ h0, const float* __restrict__ c0,
    const float* __restrict__ whhf, const float* __restrict__ whhb,
    u16* __restrict__ hfo, u16* __restrict__ hbo,
    u32* __restrict__ flags)
{
    __shared__ u16 shm[2][64][136];        // producer: gather tile; consumer: hbuf
    int tid = threadIdx.x;
    int w = tid >> 6, lane = tid & 63;
    int rg = lane >> 4, cn = lane & 15;

    if (blockIdx.x >= 8) {
        // ------------------------- PRODUCER -------------------------
        int c = blockIdx.x - 8;
        int d  = c >> 8;
        int sc = c & 255;                  // 2 s-steps
        const float* wih = d ? wihb : wihf;
        const float* bih = d ? bihb : bihf;
        const float* bhh = d ? bhhb : bhhf;
        u16* X = d ? Xb : Xf;

        short8 afr[4][4];
        #pragma unroll
        for (int mi = 0; mi < 4; ++mi) {
            int gate = gmap2(16 * (w + 8 * mi) + cn);
            #pragma unroll
            for (int kt = 0; kt < 4; ++kt) {
                const float* p = wih + (size_t)gate * 128 + kt * 32 + rg * 8;
                float4 f0 = *(const float4*)p;
                float4 f1 = *(const float4*)(p + 4);
                union { short8 v; u32 u[4]; } sv;
                sv.u[0] = pack_bf16(f0.x, f0.y);
                sv.u[1] = pack_bf16(f0.z, f0.w);
                sv.u[2] = pack_bf16(f1.x, f1.y);
                sv.u[3] = pack_bf16(f1.z, f1.w);
                afr[mi][kt] = sv.v;
            }
        }
        float bs[4][4];
        #pragma unroll
        for (int mi = 0; mi < 4; ++mi)
            #pragma unroll
            for (int r = 0; r < 4; ++r) {
                int g = gmap2(16 * (w + 8 * mi) + 4 * rg + r);
                bs[mi][r] = bih[g] + bhh[g];
            }
        {
            int row = tid >> 2, q = tid & 3;
            int sl = row >> 6, bb = row & 63;
            int tok = sent[(sc * 2 + sl) * 64 + bb];
            const float* er = emb + (size_t)tok * 128 + q * 32;
            u16* dst = &shm[sl][bb][q * 32];
            #pragma unroll
            for (int u = 0; u < 4; ++u) {
                float4 a = *(const float4*)(er + u * 8);
                float4 cc = *(const float4*)(er + u * 8 + 4);
                uint4 st;
                st.x = pack_bf16(a.x, a.y);  st.y = pack_bf16(a.z, a.w);
                st.z = pack_bf16(cc.x, cc.y); st.w = pack_bf16(cc.z, cc.w);
                *(uint4*)(dst + u * 8) = st;
            }
        }
        __syncthreads();
        #pragma unroll
        for (int ss = 0; ss < 2; ++ss) {
            int s = sc * 2 + ss;
            #pragma unroll
            for (int nt = 0; nt < 4; ++nt) {
                short8 bfr[4];
                #pragma unroll
                for (int kt = 0; kt < 4; ++kt)
                    bfr[kt] = *(const short8*)&shm[ss][nt * 16 + cn][kt * 32 + rg * 8];
                #pragma unroll
                for (int mi = 0; mi < 4; ++mi) {
                    f32x4 acc = {0.f, 0.f, 0.f, 0.f};
                    #pragma unroll
                    for (int kt = 0; kt < 4; ++kt)
                        acc = __builtin_amdgcn_mfma_f32_16x16x32_bf16(afr[mi][kt], bfr[kt], acc, 0, 0, 0);
                    size_t base = (((size_t)s * 4 + nt) * 32 + (w + 8 * mi)) * 256
                                + (size_t)rg * 64 + (size_t)cn * 4;
                    uint2 st;
                    st.x = pack_bf16((acc[0] + bs[mi][0]) * LOG2E, (acc[1] + bs[mi][1]) * LOG2E);
                    st.y = pack_bf16((acc[2] + bs[mi][2]) * LOG2E, (acc[3] + bs[mi][3]) * LOG2E);
                    *(uint2*)(X + base) = st;
                }
            }
        }
        __syncthreads();                    // drains vmcnt for all threads
        if (tid == 0)
            __hip_atomic_fetch_add(&flags[(d << 5) | (sc >> 3)], 1u,
                                   __ATOMIC_RELEASE, __HIP_MEMORY_SCOPE_AGENT);
        return;
    }

    // ------------------------- CONSUMER (LSTM) -------------------------
    __builtin_amdgcn_s_setprio(1);
    int d  = blockIdx.x >> 2, g4 = blockIdx.x & 3;
    const float* whh = d ? whhb : whhf;
    const u16*   X   = d ? Xb   : Xf;
    u16*         ho  = d ? hbo  : hfo;
    u16 (*hbuf)[16][136] = (u16(*)[16][136])&shm[0][0][0];

    short8 afr[4][4];
    #pragma unroll
    for (int mi = 0; mi < 4; ++mi) {
        int gate = gmap2(16 * (w + 8 * mi) + cn);
        #pragma unroll
        for (int kt = 0; kt < 4; ++kt) {
            const float* p = whh + (size_t)gate * 128 + kt * 32 + rg * 8;
            float4 f0 = *(const float4*)p;
            float4 f1 = *(const float4*)(p + 4);
            union { short8 v; u32 u[4]; } sv;
            sv.u[0] = pack_bf16(f0.x * LOG2E, f0.y * LOG2E);
            sv.u[1] = pack_bf16(f0.z * LOG2E, f0.w * LOG2E);
            sv.u[2] = pack_bf16(f1.x * LOG2E, f1.y * LOG2E);
            sv.u[3] = pack_bf16(f1.z * LOG2E, f1.w * LOG2E);
            afr[mi][kt] = sv.v;
        }
    }
    int b = g4 * 16 + cn;
    int chb = 16 * w + rg * 4;
    f32x2 cstA, cstB;
    {
        float4 cv = *(const float4*)(c0 + ((size_t)d * 64 + b) * 128 + chb);
        cstA.x = cv.x; cstA.y = cv.y;
        cstB.x = cv.z; cstB.y = cv.w;
    }
    {
        float4 hv = *(const float4*)(h0 + ((size_t)d * 64 + b) * 128 + chb);
        uint2 st0;
        st0.x = pack_bf16(hv.x, hv.y);
        st0.y = pack_bf16(hv.z, hv.w);
        *(uint2*)&hbuf[0][cn][chb] = st0;
    }
    __syncthreads();

    int s0 = d ? 511 : 0;
    const int sdelta = d ? -32768 : 32768;      // X u16 elems per s-step
    const ptrdiff_t hdelta = d ? -8192 : 8192;  // 64*128 u16 per s-step
    size_t lof = (size_t)rg * 64 + (size_t)cn * 4;

#define WAITC(p)                                                             \
    while (__hip_atomic_load(&flags[(d << 5) | (p)], __ATOMIC_ACQUIRE,       \
                             __HIP_MEMORY_SCOPE_AGENT) < 8u)                 \
        __builtin_amdgcn_s_sleep(8)

    WAITC(d ? 31 : 0);                      // initial prefetch covers chunk 0

    const u16* pa[4]; const u16* pb[4];
    uint2 xA[4], xB[4];
    #pragma unroll
    for (int mi = 0; mi < 4; ++mi) {
        const u16* base = X + (((size_t)s0 * 4 + g4) * 32 + (w + 8 * mi)) * 256 + lof;
        xA[mi] = *(const uint2*)base;
        xB[mi] = *(const uint2*)(base + sdelta);
        pa[mi] = base + 2 * sdelta;
        pb[mi] = base + 3 * sdelta;
    }
    u16* hop = ho + ((size_t)s0 * 64 + b) * 128 + chb;

#define LSTM_STEP(RB, WB, XC, XP)                                            \
    do {                                                                     \
        short8 bfr[4];                                                       \
        _Pragma("unroll")                                                    \
        for (int kt = 0; kt < 4; ++kt)                                       \
            bfr[kt] = *(const short8*)&hbuf[RB][cn][kt * 32 + rg * 8];       \
        f32x4 z[4];                                                          \
        _Pragma("unroll")                                                    \
        for (int mi = 0; mi < 4; ++mi) {                                     \
            f32x4 acc;                                                       \
            acc[0] = xex(XC[mi], 0); acc[1] = xex(XC[mi], 1);                \
            acc[2] = xex(XC[mi], 2); acc[3] = xex(XC[mi], 3);                \
            _Pragma("unroll")                                                \
            for (int kt = 0; kt < 4; ++kt)                                   \
                acc = __builtin_amdgcn_mfma_f32_16x16x32_bf16(               \
                    afr[mi][kt], bfr[kt], acc, 0, 0, 0);                     \
            z[mi] = acc;                                                     \
            XC[mi] = *(const uint2*)XP[mi];                                  \
            XP[mi] += 2 * sdelta;                                            \
        }                                                                    \
        f32x2 ziA = {z[0][0], z[1][0]}, zfA = {z[0][1], z[1][1]};            \
        f32x2 zgA = {z[0][2], z[1][2]}, zoA = {z[0][3], z[1][3]};            \
        f32x2 hA = lstm_pair(ziA, zfA, zgA, zoA, &cstA);                     \
        u32 pA = pack_bf16(hA.x, hA.y);                                      \
        *(u32*)&hbuf[WB][cn][chb] = pA;                                      \
        *(u32*)hop = pA;                                                     \
        f32x2 ziB = {z[2][0], z[3][0]}, zfB = {z[2][1], z[3][1]};            \
        f32x2 zgB = {z[2][2], z[3][2]}, zoB = {z[2][3], z[3][3]};            \
        f32x2 hB = lstm_pair(ziB, zfB, zgB, zoB, &cstB);                     \
        u32 pB = pack_bf16(hB.x, hB.y);                                      \
        *(u32*)&hbuf[WB][cn][chb + 2] = pB;                                  \
        *(u32*)(hop + 2) = pB;                                               \
        hop += hdelta;                                                       \
        asm volatile("s_waitcnt lgkmcnt(0)\n\ts_barrier" ::: "memory");      \
    } while (0)

    for (int it = 0; it < 256; ++it) {
        if ((it & 7) == 6) {                // prefetch crosses into chunk m
            int m = (it + 2) >> 3; if (m > 31) m = 31;
            WAITC(d ? (31 - m) : m);
        }
        LSTM_STEP(0, 1, xA, pa);
        LSTM_STEP(1, 0, xB, pb);
    }
#undef LSTM_STEP
#undef WAITC
}

// ---------------------------------------------------------------------------
// K3: feats[s,b,t] = [hf|hb] . w_out[t] + b_out[t].   block handles 32 pos.
// ---------------------------------------------------------------------------
__global__ __launch_bounds__(256) void k_feats(
    const u16* __restrict__ hf, const u16* __restrict__ hb,
    const float* __restrict__ wout, const float* __restrict__ bout,
    float* __restrict__ feats)
{
    __shared__ u16 sf[32][136], sb[32][136];
    __shared__ float wo[7][260];
    __shared__ float bo[8];
    int tid = threadIdx.x;
    int pos0 = blockIdx.x * 32;
    {
        int r = tid >> 3, cc = (tid & 7) * 16;
        const uint4* pf = (const uint4*)(hf + (size_t)(pos0 + r) * 128 + cc);
        const uint4* pb = (const uint4*)(hb + (size_t)(pos0 + r) * 128 + cc);
        *(uint4*)&sf[r][cc]     = pf[0];
        *(uint4*)&sf[r][cc + 8] = pf[1];
        *(uint4*)&sb[r][cc]     = pb[0];
        *(uint4*)&sb[r][cc + 8] = pb[1];
    }
    for (int i = tid; i < 1792; i += 256) wo[i >> 8][i & 255] = wout[i];
    if (tid < 7) bo[tid] = bout[tid];
    __syncthreads();
    int pp = tid >> 3, tt = tid & 7;
    if (tt < 7) {
        float acc = bo[tt];
        #pragma unroll 4
        for (int ch = 0; ch < 128; ch += 2) {
            u32 uf = *(const u32*)&sf[pp][ch];
            u32 ub = *(const u32*)&sb[pp][ch];
            float2 w0 = *(const float2*)&wo[tt][ch];
            float2 w1 = *(const float2*)&wo[tt][128 + ch];
            acc += __uint_as_float(uf << 16) * w0.x
                 + __uint_as_float(uf & 0xFFFF0000u) * w0.y
                 + __uint_as_float(ub << 16) * w1.x
                 + __uint_as_float(ub & 0xFFFF0000u) * w1.y;
        }
        feats[(size_t)(pos0 + pp) * 7 + tt] = acc;
    }
}

// ---------------------------------------------------------------------------
// K4a: CRF chunk fold.  block=(b, chunk of 64 steps), 512 single-wave blocks.
// M in registers (lane (i,j) holds M[i][j]); row access via __shfl.
// ---------------------------------------------------------------------------
__global__ __launch_bounds__(64) void k_crf_chunk(
    const float* __restrict__ feats, const float* __restrict__ trans,
    float* __restrict__ chunkM)
{
    int b = blockIdx.x >> 3, c = blockIdx.x & 7;
    int lane = threadIdx.x;
    int i = lane >> 3, j = lane & 7;
    __shared__ float fl[64][8];
    int s0 = c * 64;
    for (int idx = lane; idx < 448; idx += 64) {
        int ss = idx / 7, jj = idx - ss * 7;
        fl[ss][jj] = feats[(size_t)((s0 + ss) * 64 + b) * 7 + jj];
    }
    float tc[7];
    #pragma unroll
    for (int k = 0; k < 7; ++k) tc[k] = (j < 7) ? trans[k * 7 + j] : 0.f;
    bool valid = (i < 7 && j < 7);
    float M0 = valid ? trans[i * 7 + j] : -1e30f;
    __syncthreads();
    float M = M0 + (valid ? fl[0][j] : 0.f);
    for (int ss = 1; ss < 64; ++ss) {
        int rb = i * 8;
        float v0 = __shfl(M, rb + 0, 64) + tc[0];
        float v1 = __shfl(M, rb + 1, 64) + tc[1];
        float v2 = __shfl(M, rb + 2, 64) + tc[2];
        float v3 = __shfl(M, rb + 3, 64) + tc[3];
        float v4 = __shfl(M, rb + 4, 64) + tc[4];
        float v5 = __shfl(M, rb + 5, 64) + tc[5];
        float v6 = __shfl(M, rb + 6, 64) + tc[6];
        float mx = fmaxf(fmaxf(fmaxf(v0, v1), fmaxf(v2, v3)),
                         fmaxf(fmaxf(v4, v5), v6));
        float sm = __expf(v0 - mx) + __expf(v1 - mx) + __expf(v2 - mx)
                 + __expf(v3 - mx) + __expf(v4 - mx) + __expf(v5 - mx)
                 + __expf(v6 - mx);
        M = mx + __logf(sm) + fl[ss][j];
    }
    if (valid)
        chunkM[(size_t)(b * 8 + c) * 49 + i * 7 + j] = M;
}

// ---------------------------------------------------------------------------
// K4b: SINGLE-block final fold (R15 batched-gold version).
// ---------------------------------------------------------------------------
__global__ __launch_bounds__(512) void k_crf_final(
    const float* __restrict__ chunkM, const float* __restrict__ trans,
    const int* __restrict__ tags, const float* __restrict__ feats,
    float* __restrict__ out)
{
    int tid = threadIdx.x;
    int w = tid >> 6, lane = tid & 63;
    int k = lane >> 3, j = lane & 7;
    int b = w * 8 + k;
    bool jv = (j < 7);
    __shared__ float Tl[49];
    __shared__ float red[512];
    __shared__ float fsh[64];
    if (tid < 49) Tl[tid] = trans[tid];
    __syncthreads();

    float av = (j == 5) ? 0.f : -1e4f;          // alpha0
    #pragma unroll
    for (int c = 0; c < 8; ++c) {
        float a0 = __shfl(av, k * 8 + 0, 64);
        float a1 = __shfl(av, k * 8 + 1, 64);
        float a2 = __shfl(av, k * 8 + 2, 64);
        float a3 = __shfl(av, k * 8 + 3, 64);
        float a4 = __shfl(av, k * 8 + 4, 64);
        float a5 = __shfl(av, k * 8 + 5, 64);
        float a6 = __shfl(av, k * 8 + 6, 64);
        if (jv) {
            const float* Pp = chunkM + ((size_t)b * 8 + c) * 49 + j;
            float v0 = a0 + Pp[0],  v1 = a1 + Pp[7],  v2 = a2 + Pp[14];
            float v3 = a3 + Pp[21], v4 = a4 + Pp[28], v5 = a5 + Pp[35];
            float v6 = a6 + Pp[42];
            float mx = fmaxf(fmaxf(fmaxf(v0, v1), fmaxf(v2, v3)),
                             fmaxf(fmaxf(v4, v5), v6));
            float sm = __expf(v0 - mx) + __expf(v1 - mx) + __expf(v2 - mx)
                     + __expf(v3 - mx) + __expf(v4 - mx) + __expf(v5 - mx)
                     + __expf(v6 - mx);
            av = mx + __logf(sm);
        }
    }
    float u = jv ? (av + Tl[42 + j]) : -1e30f;
    float m = u;
    #pragma unroll
    for (int off = 1; off < 8; off <<= 1) m = fmaxf(m, __shfl_xor(m, off, 64));
    float e = jv ? __expf(u - m) : 0.f;
    #pragma unroll
    for (int off = 1; off < 8; off <<= 1) e += __shfl_xor(e, off, 64);
    float fwd = m + __logf(e);
    if (j == 0) fsh[b] = fwd;

    int tb = tid & 63, q = tid >> 6;
    const int* tgp = tags + (size_t)tb * 512 + q * 64;
    float acc = 0.f;
    int tp = (q == 0) ? 5 : tgp[-1];
    for (int g8 = 0; g8 < 8; ++g8) {
        int4 ta = *(const int4*)(tgp + g8 * 8);
        int4 tb4 = *(const int4*)(tgp + g8 * 8 + 4);
        int t8[8] = {ta.x, ta.y, ta.z, ta.w, tb4.x, tb4.y, tb4.z, tb4.w};
        float f8[8];
        #pragma unroll
        for (int u2 = 0; u2 < 8; ++u2)
            f8[u2] = feats[(size_t)((q * 64 + g8 * 8 + u2) * 64 + tb) * 7 + t8[u2]];
        #pragma unroll
        for (int u2 = 0; u2 < 8; ++u2) {
            acc += Tl[t8[u2] * 7 + tp] + f8[u2];
            tp = t8[u2];
        }
    }
    if (q == 7) acc += Tl[42 + tgp[63]];
    red[tid] = acc;
    __syncthreads();
    if (tid < 64) {
        float g = red[tid];
        #pragma unroll
        for (int qq = 1; qq < 8; ++qq) g += red[tid + 64 * qq];
        red[tid] = fsh[tid] - g;
    }
    __syncthreads();
    if (tid < 64) {
        float v = red[tid];
        #pragma unroll
        for (int off = 1; off < 64; off <<= 1) v += __shfl_xor(v, off, 64);
        if (tid == 0) out[0] = v * (1.0f / 64.0f);
    }
}

// ---------------------------------------------------------------------------
extern "C" void kernel_launch(void* const* d_in, const int* in_sizes, int n_in,
                              void* d_out, int out_size, void* d_ws, size_t ws_size,
                              hipStream_t stream) {
    const int*   sent = (const int*)d_in[0];
    const int*   tags = (const int*)d_in[1];
    const float* h0   = (const float*)d_in[2];
    const float* c0   = (const float*)d_in[3];
    const float* emb  = (const float*)d_in[4];
    const float* wihf = (const float*)d_in[5];
    const float* whhf = (const float*)d_in[6];
    const float* bihf = (const float*)d_in[7];
    const float* bhhf = (const float*)d_in[8];
    const float* wihb = (const float*)d_in[9];
    const float* whhb = (const float*)d_in[10];
    const float* bihb = (const float*)d_in[11];
    const float* bhhb = (const float*)d_in[12];
    const float* wout = (const float*)d_in[13];
    const float* bout = (const float*)d_in[14];
    const float* trn  = (const float*)d_in[15];

    char* ws = (char*)d_ws;
    u16*   Xf     = (u16*)(ws);                       // 33,554,432 B
    u16*   Xb     = (u16*)(ws + 33554432);            // 33,554,432 B
    u16*   hfp    = (u16*)(ws + 67108864);            //  8,388,608 B
    u16*   hbp    = (u16*)(ws + 75497472);            //  8,388,608 B
    float* feats  = (float*)(ws + 83886080);          //    917,504 B
    float* chunkM = (float*)(ws + 84803584);          //    100,352 B
    u32*   flags  = (u32*)feats;                      // 256 B, overwritten by k_feats

    hipMemsetAsync(flags, 0, 256, stream);
    k_fused<<<520, 512, 0, stream>>>(sent, emb, wihf, bihf, bhhf,
                                     wihb, bihb, bhhb, Xf, Xb,
                                     h0, c0, whhf, whhb, hfp, hbp, flags);
    k_feats<<<1024, 256, 0, stream>>>(hfp, hbp, wout, bout, feats);
    k_crf_chunk<<<512, 64, 0, stream>>>(feats, trn, chunkM);
    k_crf_final<<<1, 512, 0, stream>>>(chunkM, trn, tags, feats, (float*)d_out);
}

// Round 10
// 584.822 us; speedup vs baseline: 1.0497x; 1.0497x over previous
//
#include <hip/hip_runtime.h>

typedef unsigned int u32;
typedef unsigned short u16;
typedef __attribute__((ext_vector_type(8))) short short8;   // 8 bf16 (4 VGPRs)
typedef __attribute__((ext_vector_type(4))) float f32x4;
typedef __attribute__((ext_vector_type(2))) float f32x2;

#define DEV __device__ __forceinline__
#define LOG2E 1.44269504089f

DEV u16 f2bf(float f) {
    u32 u = __float_as_uint(f);
    return (u16)((u + 0x7FFFu + ((u >> 16) & 1u)) >> 16);
}
DEV float bf2f(u16 h) { return __uint_as_float(((u32)h) << 16); }
DEV float frcp(float x) { return __builtin_amdgcn_rcpf(x); }
DEV float fexp2(float x) {
#if __has_builtin(__builtin_amdgcn_exp2f)
    return __builtin_amdgcn_exp2f(x);
#else
    return exp2f(x);
#endif
}
DEV u32 pack_bf16(float a, float b) {
#if __has_builtin(__builtin_amdgcn_cvt_pk_bf16_f32)
    auto v = __builtin_amdgcn_cvt_pk_bf16_f32(a, b);   // lo=a, hi=b
    u32 r; __builtin_memcpy(&r, &v, 4); return r;
#else
    return (u32)f2bf(a) | ((u32)f2bf(b) << 16);
#endif
}
// extract r-th bf16 (r constant under unroll) from packed uint2
DEV float xex(uint2 v, int r) {
    u32 u = (r & 2) ? v.y : v.x;
    return (r & 1) ? __uint_as_float(u & 0xFFFF0000u) : __uint_as_float(u << 16);
}

// Gate-row permutation (R13-proven): new row g' (bit layout [mi:2][w:3][rg:2][r:2])
// maps to old gate = type r, channel 16w+4rg+mi.  Each thread's 4 acc elements
// of ONE tile are {zi,zf,zg,zo} of ONE channel; channels stay the contiguous
// quad chb..chb+3.  Applied to weight rows + biases in both kernels.
DEV int gmap2(int g) { return ((g & 3) << 7) + (g & 0x7C) + (g >> 7); }

// packed-pair helpers
DEV f32x2 exp2p(f32x2 a) { f32x2 r; r.x = fexp2(a.x); r.y = fexp2(a.y); return r; }
DEV f32x2 rcpp(f32x2 a)  { f32x2 r; r.x = frcp(a.x);  r.y = frcp(a.y);  return r; }
DEV f32x2 minp(f32x2 a, float b) { f32x2 r; r.x = fminf(a.x, b); r.y = fminf(a.y, b); return r; }

// one LSTM elementwise step on a PAIR of channels (proven op order)
DEV f32x2 lstm_pair(f32x2 zi, f32x2 zf, f32x2 zg, f32x2 zo, f32x2* cst) {
    f32x2 ei = exp2p(-zi);
    f32x2 ef = exp2p(-zf);
    f32x2 eo = exp2p(-zo);
    f32x2 eg = exp2p(minp(zg + zg, 115.f));
    f32x2 A = 1.f + ei, F = 1.f + ef, G = eg + 1.f, O = 1.f + eo;
    f32x2 AG = A * G;
    f32x2 cc = (*cst * AG + (eg - 1.f) * F) * rcpp(F * AG);
    *cst = cc;
    f32x2 ec = exp2p(minp(cc * 2.885390082f, 115.f));
    return (ec - 1.f) * rcpp(O * (ec + 1.f));
}

// ---------------------------------------------------------------------------
// K1 (R6-proven): fused embedding gather + input projection, MFMA, both dirs.
// 256 blocks = 2 dirs x 128 chunks of 4 s-steps.  X layout = C-frag-swizzled
// in gmap2 row order; pre-scaled by log2e.
// ---------------------------------------------------------------------------
__global__ __launch_bounds__(512) void k_inproj2(
    const int* __restrict__ sent, const float* __restrict__ emb,
    const float* __restrict__ wihf, const float* __restrict__ bihf, const float* __restrict__ bhhf,
    const float* __restrict__ wihb, const float* __restrict__ bihb, const float* __restrict__ bhhb,
    u16* __restrict__ Xf, u16* __restrict__ Xb)
{
    int blk = blockIdx.x;
    int d  = blk >> 7;
    int sc = blk & 127;                    // 4 s-steps per block
    const float* wih = d ? wihb : wihf;
    const float* bih = d ? bihb : bihf;
    const float* bhh = d ? bhhb : bhhf;
    u16* X = d ? Xb : Xf;
    int tid = threadIdx.x;
    int w = tid >> 6, lane = tid & 63;
    int rg = lane >> 4, cn = lane & 15;

    short8 afr[4][4];
    #pragma unroll
    for (int mi = 0; mi < 4; ++mi) {
        int gate = gmap2(16 * (w + 8 * mi) + cn);
        #pragma unroll
        for (int kt = 0; kt < 4; ++kt) {
            const float* p = wih + (size_t)gate * 128 + kt * 32 + rg * 8;
            float4 f0 = *(const float4*)p;
            float4 f1 = *(const float4*)(p + 4);
            union { short8 v; u32 u[4]; } sv;
            sv.u[0] = pack_bf16(f0.x, f0.y);
            sv.u[1] = pack_bf16(f0.z, f0.w);
            sv.u[2] = pack_bf16(f1.x, f1.y);
            sv.u[3] = pack_bf16(f1.z, f1.w);
            afr[mi][kt] = sv.v;
        }
    }
    float bs[4][4];
    #pragma unroll
    for (int mi = 0; mi < 4; ++mi)
        #pragma unroll
        for (int r = 0; r < 4; ++r) {
            int g = gmap2(16 * (w + 8 * mi) + 4 * rg + r);
            bs[mi][r] = bih[g] + bhh[g];
        }

    __shared__ u16 tile[2][64][136];
    #pragma unroll
    for (int stage = 0; stage < 2; ++stage) {
        if (stage) __syncthreads();
        {
            int row = tid >> 2, q = tid & 3;
            int sl = row >> 6, bb = row & 63;
            int tok = sent[(sc * 4 + stage * 2 + sl) * 64 + bb];
            const float* er = emb + (size_t)tok * 128 + q * 32;
            u16* dst = &tile[sl][bb][q * 32];
            #pragma unroll
            for (int u = 0; u < 4; ++u) {
                float4 a = *(const float4*)(er + u * 8);
                float4 c = *(const float4*)(er + u * 8 + 4);
                uint4 st;
                st.x = pack_bf16(a.x, a.y); st.y = pack_bf16(a.z, a.w);
                st.z = pack_bf16(c.x, c.y); st.w = pack_bf16(c.z, c.w);
                *(uint4*)(dst + u * 8) = st;
            }
        }
        __syncthreads();
        #pragma unroll
        for (int ss = 0; ss < 2; ++ss) {
            int s = sc * 4 + stage * 2 + ss;
            #pragma unroll
            for (int nt = 0; nt < 4; ++nt) {
                short8 bfr[4];
                #pragma unroll
                for (int kt = 0; kt < 4; ++kt)
                    bfr[kt] = *(const short8*)&tile[ss][nt * 16 + cn][kt * 32 + rg * 8];
                #pragma unroll
                for (int mi = 0; mi < 4; ++mi) {
                    f32x4 acc = {0.f, 0.f, 0.f, 0.f};
                    #pragma unroll
                    for (int kt = 0; kt < 4; ++kt)
                        acc = __builtin_amdgcn_mfma_f32_16x16x32_bf16(afr[mi][kt], bfr[kt], acc, 0, 0, 0);
                    size_t base = (((size_t)s * 4 + nt) * 32 + (w + 8 * mi)) * 256
                                + (size_t)rg * 64 + (size_t)cn * 4;
                    uint2 st;
                    st.x = pack_bf16((acc[0] + bs[mi][0]) * LOG2E, (acc[1] + bs[mi][1]) * LOG2E);
                    st.y = pack_bf16((acc[2] + bs[mi][2]) * LOG2E, (acc[3] + bs[mi][3]) * LOG2E);
                    *(uint2*)(X + base) = st;
                }
            }
        }
    }
}

// ---------------------------------------------------------------------------
// K2 (R13-proven, 383us): 8-wave structure + gmap2 tiling.  Also zeroes the
// k_tail ticket counter (stream-ordered before k_tail; robust to ws poison).
// ---------------------------------------------------------------------------
__global__ __launch_bounds__(512) void k_lstm(
    const float* __restrict__ h0, const float* __restrict__ c0,
    const float* __restrict__ whhf, const float* __restrict__ whhb,
    const u16* __restrict__ Xf, const u16* __restrict__ Xb,
    u16* __restrict__ hfo, u16* __restrict__ hbo, u32* __restrict__ ctr)
{
    if (blockIdx.x == 0 && threadIdx.x == 0) *ctr = 0;
    int d  = blockIdx.x >> 2, g4 = blockIdx.x & 3;
    const float* whh = d ? whhb : whhf;
    const u16*   X   = d ? Xb   : Xf;
    u16*         ho  = d ? hbo  : hfo;
    int w = threadIdx.x >> 6, lane = threadIdx.x & 63;
    int rg = lane >> 4, cn = lane & 15;

    short8 afr[4][4];
    #pragma unroll
    for (int mi = 0; mi < 4; ++mi) {
        int gate = gmap2(16 * (w + 8 * mi) + cn);
        #pragma unroll
        for (int kt = 0; kt < 4; ++kt) {
            const float* p = whh + (size_t)gate * 128 + kt * 32 + rg * 8;
            float4 f0 = *(const float4*)p;
            float4 f1 = *(const float4*)(p + 4);
            union { short8 v; u32 u[4]; } sv;
            sv.u[0] = pack_bf16(f0.x * LOG2E, f0.y * LOG2E);
            sv.u[1] = pack_bf16(f0.z * LOG2E, f0.w * LOG2E);
            sv.u[2] = pack_bf16(f1.x * LOG2E, f1.y * LOG2E);
            sv.u[3] = pack_bf16(f1.z * LOG2E, f1.w * LOG2E);
            afr[mi][kt] = sv.v;
        }
    }
    int b = g4 * 16 + cn;
    int chb = 16 * w + rg * 4;
    f32x2 cstA, cstB;
    {
        float4 cv = *(const float4*)(c0 + ((size_t)d * 64 + b) * 128 + chb);
        cstA.x = cv.x; cstA.y = cv.y;
        cstB.x = cv.z; cstB.y = cv.w;
    }
    __shared__ u16 hbuf[2][16][136];
    {
        float4 hv = *(const float4*)(h0 + ((size_t)d * 64 + b) * 128 + chb);
        uint2 st0;
        st0.x = pack_bf16(hv.x, hv.y);
        st0.y = pack_bf16(hv.z, hv.w);
        *(uint2*)&hbuf[0][cn][chb] = st0;
    }
    __syncthreads();

    int s0 = d ? 511 : 0;
    const int sdelta = d ? -32768 : 32768;
    const ptrdiff_t hdelta = d ? -8192 : 8192;
    size_t lof = (size_t)rg * 64 + (size_t)cn * 4;

    const u16* pa[4]; const u16* pb[4];
    uint2 xA[4], xB[4];
    #pragma unroll
    for (int mi = 0; mi < 4; ++mi) {
        const u16* base = X + (((size_t)s0 * 4 + g4) * 32 + (w + 8 * mi)) * 256 + lof;
        xA[mi] = *(const uint2*)base;
        xB[mi] = *(const uint2*)(base + sdelta);
        pa[mi] = base + 2 * sdelta;
        pb[mi] = base + 3 * sdelta;
    }
    u16* hop = ho + ((size_t)s0 * 64 + b) * 128 + chb;

#define LSTM_STEP(RB, WB, XC, XP)                                            \
    do {                                                                     \
        short8 bfr[4];                                                       \
        _Pragma("unroll")                                                    \
        for (int kt = 0; kt < 4; ++kt)                                       \
            bfr[kt] = *(const short8*)&hbuf[RB][cn][kt * 32 + rg * 8];       \
        f32x4 z[4];                                                          \
        _Pragma("unroll")                                                    \
        for (int mi = 0; mi < 4; ++mi) {                                     \
            f32x4 acc;                                                       \
            acc[0] = xex(XC[mi], 0); acc[1] = xex(XC[mi], 1);                \
            acc[2] = xex(XC[mi], 2); acc[3] = xex(XC[mi], 3);                \
            _Pragma("unroll")                                                \
            for (int kt = 0; kt < 4; ++kt)                                   \
                acc = __builtin_amdgcn_mfma_f32_16x16x32_bf16(               \
                    afr[mi][kt], bfr[kt], acc, 0, 0, 0);                     \
            z[mi] = acc;                                                     \
            XC[mi] = *(const uint2*)XP[mi];                                  \
            XP[mi] += 2 * sdelta;                                            \
        }                                                                    \
        f32x2 ziA = {z[0][0], z[1][0]}, zfA = {z[0][1], z[1][1]};            \
        f32x2 zgA = {z[0][2], z[1][2]}, zoA = {z[0][3], z[1][3]};            \
        f32x2 hA = lstm_pair(ziA, zfA, zgA, zoA, &cstA);                     \
        u32 pA = pack_bf16(hA.x, hA.y);                                      \
        *(u32*)&hbuf[WB][cn][chb] = pA;                                      \
        *(u32*)hop = pA;                                                     \
        f32x2 ziB = {z[2][0], z[3][0]}, zfB = {z[2][1], z[3][1]};            \
        f32x2 zgB = {z[2][2], z[3][2]}, zoB = {z[2][3], z[3][3]};            \
        f32x2 hB = lstm_pair(ziB, zfB, zgB, zoB, &cstB);                     \
        u32 pB = pack_bf16(hB.x, hB.y);                                      \
        *(u32*)&hbuf[WB][cn][chb + 2] = pB;                                  \
        *(u32*)(hop + 2) = pB;                                               \
        hop += hdelta;                                                       \
        asm volatile("s_waitcnt lgkmcnt(0)\n\ts_barrier" ::: "memory");      \
    } while (0)

    for (int it = 0; it < 256; ++it) {
        LSTM_STEP(0, 1, xA, pa);
        LSTM_STEP(1, 0, xB, pb);
    }
#undef LSTM_STEP
}

// ---------------------------------------------------------------------------
// K_TAIL (R17): ONE launch replacing feats + crf_chunk + crf_final.
// 512 blocks x 64 threads; block (b, chunk c), thread = step ss in chunk.
//  1. compute feats[s,b,0..6] on the fly (k_feats accumulation order ->
//     bit-identical values; h row held in registers, wout broadcast from LDS)
//  2. R13 register/shfl CRF chunk fold -> chunkM
//  3. per-chunk gold partial (trans + emit; STOP term in c==7)
//  4. __threadfence + agent-scope ticket; ticket 511 runs the final fold
//     (alpha over 8 chunks x 64 batches, fwd lse, gold combine, out store).
// Ticket counter zeroed by k_lstm (stream-ordered).
// ---------------------------------------------------------------------------
__global__ __launch_bounds__(64) void k_tail(
    const u16* __restrict__ hf, const u16* __restrict__ hb,
    const float* __restrict__ wout, const float* __restrict__ bout,
    const float* __restrict__ trans, const int* __restrict__ tags,
    float* __restrict__ chunkM, float* __restrict__ goldp,
    u32* __restrict__ ctr, float* __restrict__ out)
{
    int b = blockIdx.x >> 3, c = blockIdx.x & 7;
    int ss = threadIdx.x;                  // 64 threads = 64 steps
    int i = ss >> 3, j = ss & 7;
    __shared__ float fl[64][8];
    __shared__ float wo[7][260];
    __shared__ float Tl[49];
    __shared__ float bo[8];
    __shared__ float fsh[64];
    for (int q = ss; q < 1792; q += 64) wo[q >> 8][q & 255] = wout[q];
    if (ss < 49) Tl[ss] = trans[ss];
    if (ss < 7) bo[ss] = bout[ss];
    __syncthreads();

    int s = c * 64 + ss;
    union { uint4 v4[8]; u32 u[32]; } hfr, hbr;
    {
        const uint4* pf = (const uint4*)(hf + (size_t)(s * 64 + b) * 128);
        const uint4* pb = (const uint4*)(hb + (size_t)(s * 64 + b) * 128);
        #pragma unroll
        for (int u2 = 0; u2 < 8; ++u2) { hfr.v4[u2] = pf[u2]; hbr.v4[u2] = pb[u2]; }
    }
    #pragma unroll
    for (int t = 0; t < 7; ++t) {
        float acc = bo[t];
        #pragma unroll
        for (int k = 0; k < 32; ++k) {
            u32 uf = hfr.u[k];
            u32 ub = hbr.u[k];
            float2 w0 = *(const float2*)&wo[t][2 * k];
            float2 w1 = *(const float2*)&wo[t][128 + 2 * k];
            acc += __uint_as_float(uf << 16) * w0.x
                 + __uint_as_float(uf & 0xFFFF0000u) * w0.y
                 + __uint_as_float(ub << 16) * w1.x
                 + __uint_as_float(ub & 0xFFFF0000u) * w1.y;
        }
        fl[ss][t] = acc;
    }
    fl[ss][7] = 0.f;
    __syncthreads();

    // gold partial for (b, step s): trans[tn,tp] + feats[s,b,tn]
    int tn = tags[(size_t)b * 512 + s];
    int tp = (s == 0) ? 5 : tags[(size_t)b * 512 + s - 1];
    float gp = Tl[tn * 7 + tp] + fl[ss][tn];
    if (c == 7 && ss == 63) gp += Tl[42 + tn];       // STOP term
    #pragma unroll
    for (int off = 1; off < 64; off <<= 1) gp += __shfl_xor(gp, off, 64);
    if (ss == 0) goldp[b * 8 + c] = gp;

    // CRF chunk fold (R13-proven register/shfl form)
    float tc[7];
    #pragma unroll
    for (int k = 0; k < 7; ++k) tc[k] = (j < 7) ? Tl[k * 7 + j] : 0.f;
    bool valid = (i < 7 && j < 7);
    float M = valid ? (Tl[i * 7 + j] + fl[0][j]) : -1e30f;
    for (int s2 = 1; s2 < 64; ++s2) {
        int rb = i * 8;
        float v0 = __shfl(M, rb + 0, 64) + tc[0];
        float v1 = __shfl(M, rb + 1, 64) + tc[1];
        float v2 = __shfl(M, rb + 2, 64) + tc[2];
        float v3 = __shfl(M, rb + 3, 64) + tc[3];
        float v4 = __shfl(M, rb + 4, 64) + tc[4];
        float v5 = __shfl(M, rb + 5, 64) + tc[5];
        float v6 = __shfl(M, rb + 6, 64) + tc[6];
        float mx = fmaxf(fmaxf(fmaxf(v0, v1), fmaxf(v2, v3)),
                         fmaxf(fmaxf(v4, v5), v6));
        float sm = __expf(v0 - mx) + __expf(v1 - mx) + __expf(v2 - mx)
                 + __expf(v3 - mx) + __expf(v4 - mx) + __expf(v5 - mx)
                 + __expf(v6 - mx);
        M = mx + __logf(sm) + fl[s2][j];
    }
    if (valid)
        chunkM[(size_t)(b * 8 + c) * 49 + i * 7 + j] = M;

    // completion ticket; block with ticket 511 finalizes
    __threadfence();
    u32 ticket = 0;
    if (ss == 0)
        ticket = __hip_atomic_fetch_add(ctr, 1u, __ATOMIC_ACQ_REL,
                                        __HIP_MEMORY_SCOPE_AGENT);
    ticket = (u32)__shfl((int)ticket, 0, 64);
    if (ticket != 511u) return;

    // ---------------- finalizer (one block, one wave) ----------------
    bool jv = (j < 7);
    int k2 = i;                              // k2 in [0,8): batch-in-group
    for (int wg = 0; wg < 8; ++wg) {
        int b2 = wg * 8 + k2;
        float av = (j == 5) ? 0.f : -1e4f;   // alpha0
        #pragma unroll 1
        for (int c2 = 0; c2 < 8; ++c2) {
            float a0 = __shfl(av, k2 * 8 + 0, 64);
            float a1 = __shfl(av, k2 * 8 + 1, 64);
            float a2 = __shfl(av, k2 * 8 + 2, 64);
            float a3 = __shfl(av, k2 * 8 + 3, 64);
            float a4 = __shfl(av, k2 * 8 + 4, 64);
            float a5 = __shfl(av, k2 * 8 + 5, 64);
            float a6 = __shfl(av, k2 * 8 + 6, 64);
            if (jv) {
                const float* Pp = chunkM + ((size_t)b2 * 8 + c2) * 49 + j;
                float v0 = a0 + Pp[0],  v1 = a1 + Pp[7],  v2 = a2 + Pp[14];
                float v3 = a3 + Pp[21], v4 = a4 + Pp[28], v5 = a5 + Pp[35];
                float v6 = a6 + Pp[42];
                float mx = fmaxf(fmaxf(fmaxf(v0, v1), fmaxf(v2, v3)),
                                 fmaxf(fmaxf(v4, v5), v6));
                float sm = __expf(v0 - mx) + __expf(v1 - mx) + __expf(v2 - mx)
                         + __expf(v3 - mx) + __expf(v4 - mx) + __expf(v5 - mx)
                         + __expf(v6 - mx);
                av = mx + __logf(sm);
            }
        }
        float u2 = jv ? (av + Tl[42 + j]) : -1e30f;
        float m = u2;
        #pragma unroll
        for (int off = 1; off < 8; off <<= 1) m = fmaxf(m, __shfl_xor(m, off, 64));
        float e = jv ? __expf(u2 - m) : 0.f;
        #pragma unroll
        for (int off = 1; off < 8; off <<= 1) e += __shfl_xor(e, off, 64);
        if (j == 0) fsh[b2] = m + __logf(e);
    }
    __syncthreads();
    float g = 0.f;
    #pragma unroll
    for (int c3 = 0; c3 < 8; ++c3) g += goldp[ss * 8 + c3];
    float v = fsh[ss] - g;
    #pragma unroll
    for (int off = 1; off < 64; off <<= 1) v += __shfl_xor(v, off, 64);
    if (ss == 0) out[0] = v * (1.0f / 64.0f);
}

// ---------------------------------------------------------------------------
extern "C" void kernel_launch(void* const* d_in, const int* in_sizes, int n_in,
                              void* d_out, int out_size, void* d_ws, size_t ws_size,
                              hipStream_t stream) {
    const int*   sent = (const int*)d_in[0];
    const int*   tags = (const int*)d_in[1];
    const float* h0   = (const float*)d_in[2];
    const float* c0   = (const float*)d_in[3];
    const float* emb  = (const float*)d_in[4];
    const float* wihf = (const float*)d_in[5];
    const float* whhf = (const float*)d_in[6];
    const float* bihf = (const float*)d_in[7];
    const float* bhhf = (const float*)d_in[8];
    const float* wihb = (const float*)d_in[9];
    const float* whhb = (const float*)d_in[10];
    const float* bihb = (const float*)d_in[11];
    const float* bhhb = (const float*)d_in[12];
    const float* wout = (const float*)d_in[13];
    const float* bout = (const float*)d_in[14];
    const float* trn  = (const float*)d_in[15];

    char* ws = (char*)d_ws;
    u16*   Xf     = (u16*)(ws);                       // 33,554,432 B
    u16*   Xb     = (u16*)(ws + 33554432);            // 33,554,432 B
    u16*   hfp    = (u16*)(ws + 67108864);            //  8,388,608 B
    u16*   hbp    = (u16*)(ws + 75497472);            //  8,388,608 B
    float* goldp  = (float*)(ws + 83886080);          //      2,048 B
    u32*   ctr    = (u32*)(ws + 83888128);            //          4 B
    float* chunkM = (float*)(ws + 84803584);          //    100,352 B

    k_inproj2<<<256, 512, 0, stream>>>(sent, emb, wihf, bihf, bhhf,
                                       wihb, bihb, bhhb, Xf, Xb);
    k_lstm<<<8, 512, 0, stream>>>(h0, c0, whhf, whhb, Xf, Xb, hfp, hbp, ctr);
    k_tail<<<512, 64, 0, stream>>>(hfp, hbp, wout, bout, trn, tags,
                                   chunkM, goldp, ctr, (float*)d_out);
}

// Round 11
// 558.705 us; speedup vs baseline: 1.0988x; 1.0467x over previous
//
#include <hip/hip_runtime.h>

typedef unsigned int u32;
typedef unsigned short u16;
typedef __attribute__((ext_vector_type(8))) short short8;   // 8 bf16 (4 VGPRs)
typedef __attribute__((ext_vector_type(4))) float f32x4;
typedef __attribute__((ext_vector_type(2))) float f32x2;

#define DEV __device__ __forceinline__
#define LOG2E 1.44269504089f

DEV u16 f2bf(float f) {
    u32 u = __float_as_uint(f);
    return (u16)((u + 0x7FFFu + ((u >> 16) & 1u)) >> 16);
}
DEV float bf2f(u16 h) { return __uint_as_float(((u32)h) << 16); }
DEV float frcp(float x) { return __builtin_amdgcn_rcpf(x); }
DEV float fexp2(float x) {
#if __has_builtin(__builtin_amdgcn_exp2f)
    return __builtin_amdgcn_exp2f(x);
#else
    return exp2f(x);
#endif
}
DEV u32 pack_bf16(float a, float b) {
#if __has_builtin(__builtin_amdgcn_cvt_pk_bf16_f32)
    auto v = __builtin_amdgcn_cvt_pk_bf16_f32(a, b);   // lo=a, hi=b
    u32 r; __builtin_memcpy(&r, &v, 4); return r;
#else
    return (u32)f2bf(a) | ((u32)f2bf(b) << 16);
#endif
}
// extract r-th bf16 (r constant under unroll) from packed uint2
DEV float xex(uint2 v, int r) {
    u32 u = (r & 2) ? v.y : v.x;
    return (r & 1) ? __uint_as_float(u & 0xFFFF0000u) : __uint_as_float(u << 16);
}

// Gate-row permutation (R13-proven): new row g' (bit layout [mi:2][w:3][rg:2][r:2])
// maps to old gate = type r, channel 16w+4rg+mi.  Tile mi's 16 rows become
// {4 types x 4 channels}; each thread's 4 acc elements of ONE tile are
// {zi,zf,zg,zo} of ONE channel; thread's channels across tiles stay the
// CONTIGUOUS quad chb..chb+3.  Applied to weight rows + biases in BOTH kernels.
DEV int gmap2(int g) { return ((g & 3) << 7) + (g & 0x7C) + (g >> 7); }

// packed-pair helpers (numerics identical to scalar; pk ops where they exist)
DEV f32x2 exp2p(f32x2 a) { f32x2 r; r.x = fexp2(a.x); r.y = fexp2(a.y); return r; }
DEV f32x2 rcpp(f32x2 a)  { f32x2 r; r.x = frcp(a.x);  r.y = frcp(a.y);  return r; }
DEV f32x2 minp(f32x2 a, float b) { f32x2 r; r.x = fminf(a.x, b); r.y = fminf(a.y, b); return r; }

// one LSTM elementwise step on a PAIR of channels (proven op order)
DEV f32x2 lstm_pair(f32x2 zi, f32x2 zf, f32x2 zg, f32x2 zo, f32x2* cst) {
    f32x2 ei = exp2p(-zi);
    f32x2 ef = exp2p(-zf);
    f32x2 eo = exp2p(-zo);
    f32x2 eg = exp2p(minp(zg + zg, 115.f));
    f32x2 A = 1.f + ei, F = 1.f + ef, G = eg + 1.f, O = 1.f + eo;
    f32x2 AG = A * G;
    f32x2 cc = (*cst * AG + (eg - 1.f) * F) * rcpp(F * AG);
    *cst = cc;
    f32x2 ec = exp2p(minp(cc * 2.885390082f, 115.f));
    return (ec - 1.f) * rcpp(O * (ec + 1.f));
}

// ---------------------------------------------------------------------------
// K1 (R18): fused embedding gather + input projection, MFMA, both dirs.
// 256 blocks = 2 dirs x 128 chunks of 4 s-steps.  R18 change: the stage-1
// token gather (sent lookup + 8x float4 emb loads) is HOISTED into registers
// before the first barrier, so its HBM latency hides under stage-0's MFMA
// phase (compiler can't move loads across __syncthreads itself).  Numerics
// and X layout identical to R6/R13 (gmap2 rows, C-frag swizzle, log2e).
// ---------------------------------------------------------------------------
__global__ __launch_bounds__(512) void k_inproj2(
    const int* __restrict__ sent, const float* __restrict__ emb,
    const float* __restrict__ wihf, const float* __restrict__ bihf, const float* __restrict__ bhhf,
    const float* __restrict__ wihb, const float* __restrict__ bihb, const float* __restrict__ bhhb,
    u16* __restrict__ Xf, u16* __restrict__ Xb)
{
    int blk = blockIdx.x;
    int d  = blk >> 7;
    int sc = blk & 127;                    // 4 s-steps per block
    const float* wih = d ? wihb : wihf;
    const float* bih = d ? bihb : bihf;
    const float* bhh = d ? bhhb : bhhf;
    u16* X = d ? Xb : Xf;
    int tid = threadIdx.x;
    int w = tid >> 6, lane = tid & 63;
    int rg = lane >> 4, cn = lane & 15;

    short8 afr[4][4];                      // A[m=lane&15][k=(lane>>4)*8+j]
    #pragma unroll
    for (int mi = 0; mi < 4; ++mi) {
        int gate = gmap2(16 * (w + 8 * mi) + cn);   // permuted row
        #pragma unroll
        for (int kt = 0; kt < 4; ++kt) {
            const float* p = wih + (size_t)gate * 128 + kt * 32 + rg * 8;
            float4 f0 = *(const float4*)p;
            float4 f1 = *(const float4*)(p + 4);
            union { short8 v; u32 u[4]; } sv;
            sv.u[0] = pack_bf16(f0.x, f0.y);
            sv.u[1] = pack_bf16(f0.z, f0.w);
            sv.u[2] = pack_bf16(f1.x, f1.y);
            sv.u[3] = pack_bf16(f1.z, f1.w);
            afr[mi][kt] = sv.v;
        }
    }
    float bs[4][4];
    #pragma unroll
    for (int mi = 0; mi < 4; ++mi)
        #pragma unroll
        for (int r = 0; r < 4; ++r) {
            int g = gmap2(16 * (w + 8 * mi) + 4 * rg + r);
            bs[mi][r] = bih[g] + bhh[g];
        }

    __shared__ u16 tile[2][64][136];       // 2 s-steps x 64 batch x 128 ch
    int row = tid >> 2, q = tid & 3;       // 128 rows (2s x 64b), 32 ch each
    int sl = row >> 6, bb = row & 63;
    u16* dst = &tile[sl][bb][q * 32];

    // stage-0 gather -> LDS
    {
        int tok0 = sent[(sc * 4 + sl) * 64 + bb];
        const float* er0 = emb + (size_t)tok0 * 128 + q * 32;
        #pragma unroll
        for (int u = 0; u < 4; ++u) {
            float4 a = *(const float4*)(er0 + u * 8);
            float4 c = *(const float4*)(er0 + u * 8 + 4);
            uint4 st;
            st.x = pack_bf16(a.x, a.y); st.y = pack_bf16(a.z, a.w);
            st.z = pack_bf16(c.x, c.y); st.w = pack_bf16(c.z, c.w);
            *(uint4*)(dst + u * 8) = st;
        }
    }
    // HOIST stage-1 gather into registers (latency hides under stage-0 MFMA)
    float4 g1[8];
    {
        int tok1 = sent[(sc * 4 + 2 + sl) * 64 + bb];
        const float* er1 = emb + (size_t)tok1 * 128 + q * 32;
        #pragma unroll
        for (int u = 0; u < 4; ++u) {
            g1[2 * u]     = *(const float4*)(er1 + u * 8);
            g1[2 * u + 1] = *(const float4*)(er1 + u * 8 + 4);
        }
    }
    __syncthreads();

    #pragma unroll
    for (int stage = 0; stage < 2; ++stage) {
        #pragma unroll
        for (int ss = 0; ss < 2; ++ss) {
            int s = sc * 4 + stage * 2 + ss;
            #pragma unroll
            for (int nt = 0; nt < 4; ++nt) {       // N-tile = batch group g4
                short8 bfr[4];
                #pragma unroll
                for (int kt = 0; kt < 4; ++kt)
                    bfr[kt] = *(const short8*)&tile[ss][nt * 16 + cn][kt * 32 + rg * 8];
                #pragma unroll
                for (int mi = 0; mi < 4; ++mi) {
                    f32x4 acc = {0.f, 0.f, 0.f, 0.f};
                    #pragma unroll
                    for (int kt = 0; kt < 4; ++kt)
                        acc = __builtin_amdgcn_mfma_f32_16x16x32_bf16(afr[mi][kt], bfr[kt], acc, 0, 0, 0);
                    size_t base = (((size_t)s * 4 + nt) * 32 + (w + 8 * mi)) * 256
                                + (size_t)rg * 64 + (size_t)cn * 4;
                    uint2 st;
                    st.x = pack_bf16((acc[0] + bs[mi][0]) * LOG2E, (acc[1] + bs[mi][1]) * LOG2E);
                    st.y = pack_bf16((acc[2] + bs[mi][2]) * LOG2E, (acc[3] + bs[mi][3]) * LOG2E);
                    *(uint2*)(X + base) = st;
                }
            }
        }
        if (stage == 0) {
            __syncthreads();               // MFMA0 done reading tile
            #pragma unroll
            for (int u = 0; u < 4; ++u) {  // stage-1 pack+write from regs
                uint4 st;
                st.x = pack_bf16(g1[2 * u].x, g1[2 * u].y);
                st.y = pack_bf16(g1[2 * u].z, g1[2 * u].w);
                st.z = pack_bf16(g1[2 * u + 1].x, g1[2 * u + 1].y);
                st.w = pack_bf16(g1[2 * u + 1].z, g1[2 * u + 1].w);
                *(uint4*)(dst + u * 8) = st;
            }
            __syncthreads();
        }
    }
}

// ---------------------------------------------------------------------------
// K2 (R13-proven, 383us): 8-wave structure + gmap2 tiling.  Thread's tile mi
// yields {zi,zf,zg,zo} of channel chb+mi (contiguous quad).  Nonlin of pair
// (chb,chb+1) depends only on tiles 0,1 -> its trans chain overlaps tiles
// 2,3's MFMAs.  8 waves is the measured optimum (R9: 4 waves +46%, R14: 16
// waves +7%).  MFMA acc K-chained (R12: chaining is free on matrix pipe).
// ---------------------------------------------------------------------------
__global__ __launch_bounds__(512) void k_lstm(
    const float* __restrict__ h0, const float* __restrict__ c0,
    const float* __restrict__ whhf, const float* __restrict__ whhb,
    const u16* __restrict__ Xf, const u16* __restrict__ Xb,
    u16* __restrict__ hfo, u16* __restrict__ hbo)
{
    int d  = blockIdx.x >> 2, g4 = blockIdx.x & 3;
    const float* whh = d ? whhb : whhf;
    const u16*   X   = d ? Xb   : Xf;
    u16*         ho  = d ? hbo  : hfo;
    int w = threadIdx.x >> 6, lane = threadIdx.x & 63;
    int rg = lane >> 4, cn = lane & 15;

    short8 afr[4][4];                  // whh * log2e, A-frag layout (gmap2 rows)
    #pragma unroll
    for (int mi = 0; mi < 4; ++mi) {
        int gate = gmap2(16 * (w + 8 * mi) + cn);
        #pragma unroll
        for (int kt = 0; kt < 4; ++kt) {
            const float* p = whh + (size_t)gate * 128 + kt * 32 + rg * 8;
            float4 f0 = *(const float4*)p;
            float4 f1 = *(const float4*)(p + 4);
            union { short8 v; u32 u[4]; } sv;
            sv.u[0] = pack_bf16(f0.x * LOG2E, f0.y * LOG2E);
            sv.u[1] = pack_bf16(f0.z * LOG2E, f0.w * LOG2E);
            sv.u[2] = pack_bf16(f1.x * LOG2E, f1.y * LOG2E);
            sv.u[3] = pack_bf16(f1.z * LOG2E, f1.w * LOG2E);
            afr[mi][kt] = sv.v;
        }
    }
    int b = g4 * 16 + cn;
    int chb = 16 * w + rg * 4;         // thread's channel quad
    f32x2 cstA, cstB;                  // c for (chb,chb+1) / (chb+2,chb+3)
    {
        float4 cv = *(const float4*)(c0 + ((size_t)d * 64 + b) * 128 + chb);
        cstA.x = cv.x; cstA.y = cv.y;
        cstB.x = cv.z; cstB.y = cv.w;
    }
    __shared__ u16 hbuf[2][16][136];
    {
        float4 hv = *(const float4*)(h0 + ((size_t)d * 64 + b) * 128 + chb);
        uint2 st0;
        st0.x = pack_bf16(hv.x, hv.y);
        st0.y = pack_bf16(hv.z, hv.w);
        *(uint2*)&hbuf[0][cn][chb] = st0;
    }
    __syncthreads();

    int s0 = d ? 511 : 0;
    const int sdelta = d ? -32768 : 32768;      // X u16 elems per s-step
    const ptrdiff_t hdelta = d ? -8192 : 8192;  // 64*128 u16 per s-step
    size_t lof = (size_t)rg * 64 + (size_t)cn * 4;

    const u16* pa[4]; const u16* pb[4];
    uint2 xA[4], xB[4];
    #pragma unroll
    for (int mi = 0; mi < 4; ++mi) {
        const u16* base = X + (((size_t)s0 * 4 + g4) * 32 + (w + 8 * mi)) * 256 + lof;
        xA[mi] = *(const uint2*)base;
        xB[mi] = *(const uint2*)(base + sdelta);
        pa[mi] = base + 2 * sdelta;
        pb[mi] = base + 3 * sdelta;
    }
    u16* hop = ho + ((size_t)s0 * 64 + b) * 128 + chb;

#define LSTM_STEP(RB, WB, XC, XP)                                            \
    do {                                                                     \
        short8 bfr[4];                                                       \
        _Pragma("unroll")                                                    \
        for (int kt = 0; kt < 4; ++kt)                                       \
            bfr[kt] = *(const short8*)&hbuf[RB][cn][kt * 32 + rg * 8];       \
        f32x4 z[4];                                                          \
        _Pragma("unroll")                                                    \
        for (int mi = 0; mi < 4; ++mi) {                                     \
            f32x4 acc;                                                       \
            acc[0] = xex(XC[mi], 0); acc[1] = xex(XC[mi], 1);                \
            acc[2] = xex(XC[mi], 2); acc[3] = xex(XC[mi], 3);                \
            _Pragma("unroll")                                                \
            for (int kt = 0; kt < 4; ++kt)                                   \
                acc = __builtin_amdgcn_mfma_f32_16x16x32_bf16(               \
                    afr[mi][kt], bfr[kt], acc, 0, 0, 0);                     \
            z[mi] = acc;                                                     \
            XC[mi] = *(const uint2*)XP[mi];                                  \
            XP[mi] += 2 * sdelta;                                            \
        }                                                                    \
        f32x2 ziA = {z[0][0], z[1][0]}, zfA = {z[0][1], z[1][1]};            \
        f32x2 zgA = {z[0][2], z[1][2]}, zoA = {z[0][3], z[1][3]};            \
        f32x2 hA = lstm_pair(ziA, zfA, zgA, zoA, &cstA);                     \
        u32 pA = pack_bf16(hA.x, hA.y);                                      \
        *(u32*)&hbuf[WB][cn][chb] = pA;                                      \
        *(u32*)hop = pA;                                                     \
        f32x2 ziB = {z[2][0], z[3][0]}, zfB = {z[2][1], z[3][1]};            \
        f32x2 zgB = {z[2][2], z[3][2]}, zoB = {z[2][3], z[3][3]};            \
        f32x2 hB = lstm_pair(ziB, zfB, zgB, zoB, &cstB);                     \
        u32 pB = pack_bf16(hB.x, hB.y);                                      \
        *(u32*)&hbuf[WB][cn][chb + 2] = pB;                                  \
        *(u32*)(hop + 2) = pB;                                               \
        hop += hdelta;                                                       \
        asm volatile("s_waitcnt lgkmcnt(0)\n\ts_barrier" ::: "memory");      \
    } while (0)

    for (int it = 0; it < 256; ++it) {
        LSTM_STEP(0, 1, xA, pa);
        LSTM_STEP(1, 0, xB, pb);
    }
#undef LSTM_STEP
}

// ---------------------------------------------------------------------------
// K3: feats[s,b,t] = [hf|hb] . w_out[t] + b_out[t].   block handles 32 pos.
// Paired reads (u32 for bf16 pairs, float2 for weights) halve LDS insts.
// ---------------------------------------------------------------------------
__global__ __launch_bounds__(256) void k_feats(
    const u16* __restrict__ hf, const u16* __restrict__ hb,
    const float* __restrict__ wout, const float* __restrict__ bout,
    float* __restrict__ feats)
{
    __shared__ u16 sf[32][136], sb[32][136];
    __shared__ float wo[7][260];
    __shared__ float bo[8];
    int tid = threadIdx.x;
    int pos0 = blockIdx.x * 32;
    {
        int r = tid >> 3, cc = (tid & 7) * 16;
        const uint4* pf = (const uint4*)(hf + (size_t)(pos0 + r) * 128 + cc);
        const uint4* pb = (const uint4*)(hb + (size_t)(pos0 + r) * 128 + cc);
        *(uint4*)&sf[r][cc]     = pf[0];
        *(uint4*)&sf[r][cc + 8] = pf[1];
        *(uint4*)&sb[r][cc]     = pb[0];
        *(uint4*)&sb[r][cc + 8] = pb[1];
    }
    for (int i = tid; i < 1792; i += 256) wo[i >> 8][i & 255] = wout[i];
    if (tid < 7) bo[tid] = bout[tid];
    __syncthreads();
    int pp = tid >> 3, tt = tid & 7;
    if (tt < 7) {
        float acc = bo[tt];
        #pragma unroll 4
        for (int ch = 0; ch < 128; ch += 2) {
            u32 uf = *(const u32*)&sf[pp][ch];
            u32 ub = *(const u32*)&sb[pp][ch];
            float2 w0 = *(const float2*)&wo[tt][ch];
            float2 w1 = *(const float2*)&wo[tt][128 + ch];
            acc += __uint_as_float(uf << 16) * w0.x
                 + __uint_as_float(uf & 0xFFFF0000u) * w0.y
                 + __uint_as_float(ub << 16) * w1.x
                 + __uint_as_float(ub & 0xFFFF0000u) * w1.y;
        }
        feats[(size_t)(pos0 + pp) * 7 + tt] = acc;
    }
}

// ---------------------------------------------------------------------------
// K4a: CRF chunk fold.  block=(b, chunk of 64 steps), 512 single-wave blocks.
// M in registers (lane (i,j) holds M[i][j]); row access via __shfl.
// ---------------------------------------------------------------------------
__global__ __launch_bounds__(64) void k_crf_chunk(
    const float* __restrict__ feats, const float* __restrict__ trans,
    float* __restrict__ chunkM)
{
    int b = blockIdx.x >> 3, c = blockIdx.x & 7;
    int lane = threadIdx.x;
    int i = lane >> 3, j = lane & 7;
    __shared__ float fl[64][8];
    int s0 = c * 64;
    for (int idx = lane; idx < 448; idx += 64) {
        int ss = idx / 7, jj = idx - ss * 7;
        fl[ss][jj] = feats[(size_t)((s0 + ss) * 64 + b) * 7 + jj];
    }
    float tc[7];
    #pragma unroll
    for (int k = 0; k < 7; ++k) tc[k] = (j < 7) ? trans[k * 7 + j] : 0.f;
    bool valid = (i < 7 && j < 7);
    float M0 = valid ? trans[i * 7 + j] : -1e30f;
    __syncthreads();
    float M = M0 + (valid ? fl[0][j] : 0.f);
    for (int ss = 1; ss < 64; ++ss) {
        int rb = i * 8;
        float v0 = __shfl(M, rb + 0, 64) + tc[0];
        float v1 = __shfl(M, rb + 1, 64) + tc[1];
        float v2 = __shfl(M, rb + 2, 64) + tc[2];
        float v3 = __shfl(M, rb + 3, 64) + tc[3];
        float v4 = __shfl(M, rb + 4, 64) + tc[4];
        float v5 = __shfl(M, rb + 5, 64) + tc[5];
        float v6 = __shfl(M, rb + 6, 64) + tc[6];
        float mx = fmaxf(fmaxf(fmaxf(v0, v1), fmaxf(v2, v3)),
                         fmaxf(fmaxf(v4, v5), v6));
        float sm = __expf(v0 - mx) + __expf(v1 - mx) + __expf(v2 - mx)
                 + __expf(v3 - mx) + __expf(v4 - mx) + __expf(v5 - mx)
                 + __expf(v6 - mx);
        M = mx + __logf(sm) + fl[ss][j];
    }
    if (valid)
        chunkM[(size_t)(b * 8 + c) * 49 + i * 7 + j] = M;
}

// ---------------------------------------------------------------------------
// K4b: SINGLE-block final fold.  8 waves x 8 batches; lane = k*8+j
// handles (batch w*8+k, tag j).  Folds 8 chunk matrices via shuffle-lse,
// adds STOP row, computes gold with all 512 threads, block-reduces, and
// writes d_out[0] with a plain store.
// ---------------------------------------------------------------------------
__global__ __launch_bounds__(512) void k_crf_final(
    const float* __restrict__ chunkM, const float* __restrict__ trans,
    const int* __restrict__ tags, const float* __restrict__ feats,
    float* __restrict__ out)
{
    int tid = threadIdx.x;
    int w = tid >> 6, lane = tid & 63;
    int k = lane >> 3, j = lane & 7;
    int b = w * 8 + k;
    bool jv = (j < 7);
    __shared__ float Tl[49];
    __shared__ float red[512];
    __shared__ float fsh[64];
    if (tid < 49) Tl[tid] = trans[tid];
    __syncthreads();

    float av = (j == 5) ? 0.f : -1e4f;          // alpha0
    #pragma unroll
    for (int c = 0; c < 8; ++c) {
        float a0 = __shfl(av, k * 8 + 0, 64);
        float a1 = __shfl(av, k * 8 + 1, 64);
        float a2 = __shfl(av, k * 8 + 2, 64);
        float a3 = __shfl(av, k * 8 + 3, 64);
        float a4 = __shfl(av, k * 8 + 4, 64);
        float a5 = __shfl(av, k * 8 + 5, 64);
        float a6 = __shfl(av, k * 8 + 6, 64);
        if (jv) {
            const float* Pp = chunkM + ((size_t)b * 8 + c) * 49 + j;
            float v0 = a0 + Pp[0],  v1 = a1 + Pp[7],  v2 = a2 + Pp[14];
            float v3 = a3 + Pp[21], v4 = a4 + Pp[28], v5 = a5 + Pp[35];
            float v6 = a6 + Pp[42];
            float mx = fmaxf(fmaxf(fmaxf(v0, v1), fmaxf(v2, v3)),
                             fmaxf(fmaxf(v4, v5), v6));
            float sm = __expf(v0 - mx) + __expf(v1 - mx) + __expf(v2 - mx)
                     + __expf(v3 - mx) + __expf(v4 - mx) + __expf(v5 - mx)
                     + __expf(v6 - mx);
            av = mx + __logf(sm);
        }
    }
    // fwd = lse_j(av[j] + trans[STOP=6][j]) over the 8-lane j-group
    float u = jv ? (av + Tl[42 + j]) : -1e30f;
    float m = u;
    #pragma unroll
    for (int off = 1; off < 8; off <<= 1) m = fmaxf(m, __shfl_xor(m, off, 64));
    float e = jv ? __expf(u - m) : 0.f;
    #pragma unroll
    for (int off = 1; off < 8; off <<= 1) e += __shfl_xor(e, off, 64);
    float fwd = m + __logf(e);
    if (j == 0) fsh[b] = fwd;

    // gold: thread handles batch tb, quarter q (64 steps each)
    int tb = tid & 63, q = tid >> 6;
    const int* tgp = tags + (size_t)tb * 512;
    float acc = 0.f;
    int tp = (q == 0) ? 5 : tgp[q * 64 - 1];
    for (int ss = q * 64; ss < q * 64 + 64; ++ss) {
        int tn = tgp[ss];
        acc += Tl[tn * 7 + tp] + feats[(size_t)(ss * 64 + tb) * 7 + tn];
        tp = tn;
    }
    if (q == 7) acc += Tl[42 + tgp[511]];
    red[tid] = acc;
    __syncthreads();
    if (tid < 64) {
        float g = red[tid];
        #pragma unroll
        for (int qq = 1; qq < 8; ++qq) g += red[tid + 64 * qq];
        red[tid] = fsh[tid] - g;
    }
    __syncthreads();
    if (tid < 64) {
        float v = red[tid];
        #pragma unroll
        for (int off = 1; off < 64; off <<= 1) v += __shfl_xor(v, off, 64);
        if (tid == 0) out[0] = v * (1.0f / 64.0f);
    }
}

// ---------------------------------------------------------------------------
extern "C" void kernel_launch(void* const* d_in, const int* in_sizes, int n_in,
                              void* d_out, int out_size, void* d_ws, size_t ws_size,
                              hipStream_t stream) {
    const int*   sent = (const int*)d_in[0];
    const int*   tags = (const int*)d_in[1];
    const float* h0   = (const float*)d_in[2];
    const float* c0   = (const float*)d_in[3];
    const float* emb  = (const float*)d_in[4];
    const float* wihf = (const float*)d_in[5];
    const float* whhf = (const float*)d_in[6];
    const float* bihf = (const float*)d_in[7];
    const float* bhhf = (const float*)d_in[8];
    const float* wihb = (const float*)d_in[9];
    const float* whhb = (const float*)d_in[10];
    const float* bihb = (const float*)d_in[11];
    const float* bhhb = (const float*)d_in[12];
    const float* wout = (const float*)d_in[13];
    const float* bout = (const float*)d_in[14];
    const float* trn  = (const float*)d_in[15];

    char* ws = (char*)d_ws;
    u16*   Xf     = (u16*)(ws);                       // 33,554,432 B
    u16*   Xb     = (u16*)(ws + 33554432);            // 33,554,432 B
    u16*   hfp    = (u16*)(ws + 67108864);            //  8,388,608 B
    u16*   hbp    = (u16*)(ws + 75497472);            //  8,388,608 B
    float* feats  = (float*)(ws + 83886080);          //    917,504 B
    float* chunkM = (float*)(ws + 84803584);          //    100,352 B

    k_inproj2<<<256, 512, 0, stream>>>(sent, emb, wihf, bihf, bhhf,
                                       wihb, bihb, bhhb, Xf, Xb);
    k_lstm<<<8, 512, 0, stream>>>(h0, c0, whhf, whhb, Xf, Xb, hfp, hbp);
    k_feats<<<1024, 256, 0, stream>>>(hfp, hbp, wout, bout, feats);
    k_crf_chunk<<<512, 64, 0, stream>>>(feats, trn, chunkM);
    k_crf_final<<<1, 512, 0, stream>>>(chunkM, trn, tags, feats, (float*)d_out);
}

// Round 13
// 483.647 us; speedup vs baseline: 1.2693x; 1.1552x over previous
//
#include <hip/hip_runtime.h>

typedef unsigned int u32;
typedef unsigned short u16;
typedef __attribute__((ext_vector_type(8))) short short8;   // 8 bf16 (4 VGPRs)
typedef __attribute__((ext_vector_type(4))) float f32x4;
typedef __attribute__((ext_vector_type(2))) float f32x2;

#define DEV __device__ __forceinline__
#define LOG2E 1.44269504089f

DEV u16 f2bf(float f) {
    u32 u = __float_as_uint(f);
    return (u16)((u + 0x7FFFu + ((u >> 16) & 1u)) >> 16);
}
DEV float bf2f(u16 h) { return __uint_as_float(((u32)h) << 16); }
DEV float frcp(float x) { return __builtin_amdgcn_rcpf(x); }
DEV float fexp2(float x) {
#if __has_builtin(__builtin_amdgcn_exp2f)
    return __builtin_amdgcn_exp2f(x);
#else
    return exp2f(x);
#endif
}
DEV u32 pack_bf16(float a, float b) {
#if __has_builtin(__builtin_amdgcn_cvt_pk_bf16_f32)
    auto v = __builtin_amdgcn_cvt_pk_bf16_f32(a, b);   // lo=a, hi=b
    u32 r; __builtin_memcpy(&r, &v, 4); return r;
#else
    return (u32)f2bf(a) | ((u32)f2bf(b) << 16);
#endif
}
// extract r-th bf16 (r constant under unroll) from packed uint2
DEV float xex(uint2 v, int r) {
    u32 u = (r & 2) ? v.y : v.x;
    return (r & 1) ? __uint_as_float(u & 0xFFFF0000u) : __uint_as_float(u << 16);
}

// cross-lane exchange lane <-> lane^8 within each 16-lane row.
// DPP row_ror:8 (0x128) = pure VALU op; no LDS-pipe traffic (vs ds_bpermute).
DEV float dpp8(float x) {
#if __has_builtin(__builtin_amdgcn_mov_dpp)
    return __int_as_float(
        __builtin_amdgcn_mov_dpp(__float_as_int(x), 0x128, 0xf, 0xf, true));
#else
    return __shfl_xor(x, 8, 16);
#endif
}

// Gate-row permutation (R13-proven): new row g' (bit layout [mi:2][w:3][rg:2][r:2])
// maps to old gate = type r, channel 16w+4rg+mi.  Each thread's 4 acc elements
// of ONE tile are {zi,zf,zg,zo} of ONE channel; thread's channels across tiles
// stay the CONTIGUOUS quad chb..chb+3.  Applied to weights+biases in BOTH kernels.
DEV int gmap2(int g) { return ((g & 3) << 7) + (g & 0x7C) + (g >> 7); }

// packed-pair helpers (numerics identical to scalar; pk ops where they exist)
DEV f32x2 exp2p(f32x2 a) { f32x2 r; r.x = fexp2(a.x); r.y = fexp2(a.y); return r; }
DEV f32x2 rcpp(f32x2 a)  { f32x2 r; r.x = frcp(a.x);  r.y = frcp(a.y);  return r; }
DEV f32x2 minp(f32x2 a, float b) { f32x2 r; r.x = fminf(a.x, b); r.y = fminf(a.y, b); return r; }

// one LSTM elementwise step on a PAIR of channels (proven op order)
DEV f32x2 lstm_pair(f32x2 zi, f32x2 zf, f32x2 zg, f32x2 zo, f32x2* cst) {
    f32x2 ei = exp2p(-zi);
    f32x2 ef = exp2p(-zf);
    f32x2 eo = exp2p(-zo);
    f32x2 eg = exp2p(minp(zg + zg, 115.f));
    f32x2 A = 1.f + ei, F = 1.f + ef, G = eg + 1.f, O = 1.f + eo;
    f32x2 AG = A * G;
    f32x2 cc = (*cst * AG + (eg - 1.f) * F) * rcpp(F * AG);
    *cst = cc;
    f32x2 ec = exp2p(minp(cc * 2.885390082f, 115.f));
    return (ec - 1.f) * rcpp(O * (ec + 1.f));
}

// ---------------------------------------------------------------------------
// K1 (R18-proven): fused embedding gather + input projection, MFMA, both dirs.
// 256 blocks = 2 dirs x 128 chunks of 4 s-steps.  Stage-1 gather hoisted into
// registers before the first barrier (HBM latency hides under stage-0 MFMA).
// X layout: gmap2 rows, C-frag swizzle, pre-scaled by log2e.
// ---------------------------------------------------------------------------
__global__ __launch_bounds__(512) void k_inproj2(
    const int* __restrict__ sent, const float* __restrict__ emb,
    const float* __restrict__ wihf, const float* __restrict__ bihf, const float* __restrict__ bhhf,
    const float* __restrict__ wihb, const float* __restrict__ bihb, const float* __restrict__ bhhb,
    u16* __restrict__ Xf, u16* __restrict__ Xb)
{
    int blk = blockIdx.x;
    int d  = blk >> 7;
    int sc = blk & 127;                    // 4 s-steps per block
    const float* wih = d ? wihb : wihf;
    const float* bih = d ? bihb : bihf;
    const float* bhh = d ? bhhb : bhhf;
    u16* X = d ? Xb : Xf;
    int tid = threadIdx.x;
    int w = tid >> 6, lane = tid & 63;
    int rg = lane >> 4, cn = lane & 15;

    short8 afr[4][4];                      // A[m=lane&15][k=(lane>>4)*8+j]
    #pragma unroll
    for (int mi = 0; mi < 4; ++mi) {
        int gate = gmap2(16 * (w + 8 * mi) + cn);   // permuted row
        #pragma unroll
        for (int kt = 0; kt < 4; ++kt) {
            const float* p = wih + (size_t)gate * 128 + kt * 32 + rg * 8;
            float4 f0 = *(const float4*)p;
            float4 f1 = *(const float4*)(p + 4);
            union { short8 v; u32 u[4]; } sv;
            sv.u[0] = pack_bf16(f0.x, f0.y);
            sv.u[1] = pack_bf16(f0.z, f0.w);
            sv.u[2] = pack_bf16(f1.x, f1.y);
            sv.u[3] = pack_bf16(f1.z, f1.w);
            afr[mi][kt] = sv.v;
        }
    }
    float bs[4][4];
    #pragma unroll
    for (int mi = 0; mi < 4; ++mi)
        #pragma unroll
        for (int r = 0; r < 4; ++r) {
            int g = gmap2(16 * (w + 8 * mi) + 4 * rg + r);
            bs[mi][r] = bih[g] + bhh[g];
        }

    __shared__ u16 tile[2][64][136];       // 2 s-steps x 64 batch x 128 ch
    int row = tid >> 2, q = tid & 3;       // 128 rows (2s x 64b), 32 ch each
    int sl = row >> 6, bb = row & 63;
    u16* dst = &tile[sl][bb][q * 32];

    // stage-0 gather -> LDS
    {
        int tok0 = sent[(sc * 4 + sl) * 64 + bb];
        const float* er0 = emb + (size_t)tok0 * 128 + q * 32;
        #pragma unroll
        for (int u = 0; u < 4; ++u) {
            float4 a = *(const float4*)(er0 + u * 8);
            float4 c = *(const float4*)(er0 + u * 8 + 4);
            uint4 st;
            st.x = pack_bf16(a.x, a.y); st.y = pack_bf16(a.z, a.w);
            st.z = pack_bf16(c.x, c.y); st.w = pack_bf16(c.z, c.w);
            *(uint4*)(dst + u * 8) = st;
        }
    }
    // HOIST stage-1 gather into registers (latency hides under stage-0 MFMA)
    float4 g1[8];
    {
        int tok1 = sent[(sc * 4 + 2 + sl) * 64 + bb];
        const float* er1 = emb + (size_t)tok1 * 128 + q * 32;
        #pragma unroll
        for (int u = 0; u < 4; ++u) {
            g1[2 * u]     = *(const float4*)(er1 + u * 8);
            g1[2 * u + 1] = *(const float4*)(er1 + u * 8 + 4);
        }
    }
    __syncthreads();

    #pragma unroll
    for (int stage = 0; stage < 2; ++stage) {
        #pragma unroll
        for (int ss = 0; ss < 2; ++ss) {
            int s = sc * 4 + stage * 2 + ss;
            #pragma unroll
            for (int nt = 0; nt < 4; ++nt) {       // N-tile = batch group of 16
                short8 bfr[4];
                #pragma unroll
                for (int kt = 0; kt < 4; ++kt)
                    bfr[kt] = *(const short8*)&tile[ss][nt * 16 + cn][kt * 32 + rg * 8];
                #pragma unroll
                for (int mi = 0; mi < 4; ++mi) {
                    f32x4 acc = {0.f, 0.f, 0.f, 0.f};
                    #pragma unroll
                    for (int kt = 0; kt < 4; ++kt)
                        acc = __builtin_amdgcn_mfma_f32_16x16x32_bf16(afr[mi][kt], bfr[kt], acc, 0, 0, 0);
                    size_t base = (((size_t)s * 4 + nt) * 32 + (w + 8 * mi)) * 256
                                + (size_t)rg * 64 + (size_t)cn * 4;
                    uint2 st;
                    st.x = pack_bf16((acc[0] + bs[mi][0]) * LOG2E, (acc[1] + bs[mi][1]) * LOG2E);
                    st.y = pack_bf16((acc[2] + bs[mi][2]) * LOG2E, (acc[3] + bs[mi][3]) * LOG2E);
                    *(uint2*)(X + base) = st;
                }
            }
        }
        if (stage == 0) {
            __syncthreads();               // MFMA0 done reading tile
            #pragma unroll
            for (int u = 0; u < 4; ++u) {  // stage-1 pack+write from regs
                uint4 st;
                st.x = pack_bf16(g1[2 * u].x, g1[2 * u].y);
                st.y = pack_bf16(g1[2 * u].z, g1[2 * u].w);
                st.z = pack_bf16(g1[2 * u + 1].x, g1[2 * u + 1].y);
                st.w = pack_bf16(g1[2 * u + 1].z, g1[2 * u + 1].w);
                *(uint4*)(dst + u * 8) = st;
            }
            __syncthreads();
        }
    }
}

// ---------------------------------------------------------------------------
// K2 (R19): 16 blocks = 2 dirs x 8 batch-groups of EIGHT.  MFMA N-tile has 8
// valid cols (cols 8-15 multiply zeroed h rows -> wasted MFMA, which has 6x
// headroom).  The 32 lanes with cn>=8 take over pair-B {chb+2,chb+3} of lane
// cn-8 via DPP row_ror:8 (VALU-only exchange) -> every lane runs ONE
// lstm_pair: trans instrs/wave 28->14, nonlin pk ~40->~20, writes 4->2.
// Numerics bit-identical to R13 (same pairings, same op order).  X layout
// unchanged: reader col (g8&1)*8+cn == batch g8*8+cn in tile nt=g8>>1.
// Per-CU: 8 waves (2/SIMD), same LDS reads -- only issue load halves.
// ---------------------------------------------------------------------------
__global__ __launch_bounds__(512) void k_lstm(
    const float* __restrict__ h0, const float* __restrict__ c0,
    const float* __restrict__ whhf, const float* __restrict__ whhb,
    const u16* __restrict__ Xf, const u16* __restrict__ Xb,
    u16* __restrict__ hfo, u16* __restrict__ hbo)
{
    int d  = blockIdx.x >> 3, g8 = blockIdx.x & 7;
    const float* whh = d ? whhb : whhf;
    const u16*   X   = d ? Xb   : Xf;
    u16*         ho  = d ? hbo  : hfo;
    int w = threadIdx.x >> 6, lane = threadIdx.x & 63;
    int rg = lane >> 4, cn = lane & 15;
    bool lo = (cn < 8);

    short8 afr[4][4];                  // whh * log2e, A-frag layout (gmap2 rows)
    #pragma unroll
    for (int mi = 0; mi < 4; ++mi) {
        int gate = gmap2(16 * (w + 8 * mi) + cn);
        #pragma unroll
        for (int kt = 0; kt < 4; ++kt) {
            const float* p = whh + (size_t)gate * 128 + kt * 32 + rg * 8;
            float4 f0 = *(const float4*)p;
            float4 f1 = *(const float4*)(p + 4);
            union { short8 v; u32 u[4]; } sv;
            sv.u[0] = pack_bf16(f0.x * LOG2E, f0.y * LOG2E);
            sv.u[1] = pack_bf16(f0.z * LOG2E, f0.w * LOG2E);
            sv.u[2] = pack_bf16(f1.x * LOG2E, f1.y * LOG2E);
            sv.u[3] = pack_bf16(f1.z * LOG2E, f1.w * LOG2E);
            afr[mi][kt] = sv.v;
        }
    }
    int b8  = g8 * 8 + (cn & 7);       // this lane's batch
    int chb = 16 * w + rg * 4;
    int wcol = chb + (lo ? 0 : 2);     // this lane's channel pair base
    f32x2 cst;
    {
        float2 cv = *(const float2*)(c0 + ((size_t)d * 64 + b8) * 128 + wcol);
        cst.x = cv.x; cst.y = cv.y;
    }
    __shared__ u16 hbuf[2][16][136];
    {
        float2 hv = *(const float2*)(h0 + ((size_t)d * 64 + b8) * 128 + wcol);
        *(u32*)&hbuf[0][cn & 7][wcol] = pack_bf16(hv.x, hv.y);
    }
    // zero rows 8-15 of both buffers (B-frag cols 8-15 read them -> z=0 there)
    for (int i = threadIdx.x; i < 1088; i += 512) {   // 2 bufs x 8 rows x 68 u32
        int buf = i >= 544; int rr = (i - buf * 544) / 68; int cc2 = (i - buf * 544) % 68;
        *(u32*)&hbuf[buf][8 + rr][cc2 * 2] = 0;
    }
    __syncthreads();

    int s0 = d ? 511 : 0;
    const int sdelta = d ? -32768 : 32768;      // X u16 elems per s-step
    const ptrdiff_t hdelta = d ? -8192 : 8192;  // 64*128 u16 per s-step
    size_t lof = (size_t)rg * 64 + (size_t)((g8 & 1) * 8 + (cn & 7)) * 4;

    const u16* pa[4]; const u16* pb[4];
    uint2 xA[4], xB[4];
    #pragma unroll
    for (int mi = 0; mi < 4; ++mi) {
        const u16* base = X + (((size_t)s0 * 4 + (g8 >> 1)) * 32 + (w + 8 * mi)) * 256 + lof;
        xA[mi] = *(const uint2*)base;
        xB[mi] = *(const uint2*)(base + sdelta);
        pa[mi] = base + 2 * sdelta;
        pb[mi] = base + 3 * sdelta;
    }
    u16* hop = ho + ((size_t)s0 * 64 + b8) * 128 + wcol;

#define LSTM_STEP(RB, WB, XC, XP)                                            \
    do {                                                                     \
        short8 bfr[4];                                                       \
        _Pragma("unroll")                                                    \
        for (int kt = 0; kt < 4; ++kt)                                       \
            bfr[kt] = *(const short8*)&hbuf[RB][cn][kt * 32 + rg * 8];       \
        f32x4 z[4];                                                          \
        _Pragma("unroll")                                                    \
        for (int mi = 0; mi < 4; ++mi) {                                     \
            f32x4 acc;                                                       \
            acc[0] = xex(XC[mi], 0); acc[1] = xex(XC[mi], 1);                \
            acc[2] = xex(XC[mi], 2); acc[3] = xex(XC[mi], 3);                \
            _Pragma("unroll")                                                \
            for (int kt = 0; kt < 4; ++kt)                                   \
                acc = __builtin_amdgcn_mfma_f32_16x16x32_bf16(               \
                    afr[mi][kt], bfr[kt], acc, 0, 0, 0);                     \
            z[mi] = acc;                                                     \
            XC[mi] = *(const uint2*)XP[mi];                                  \
            XP[mi] += 2 * sdelta;                                            \
        }                                                                    \
        f32x4 t2, t3;                                                        \
        _Pragma("unroll")                                                    \
        for (int r = 0; r < 4; ++r) { t2[r] = dpp8(z[2][r]);                 \
                                      t3[r] = dpp8(z[3][r]); }               \
        f32x4 za, zb;                                                        \
        _Pragma("unroll")                                                    \
        for (int r = 0; r < 4; ++r) { za[r] = lo ? z[0][r] : t2[r];          \
                                      zb[r] = lo ? z[1][r] : t3[r]; }        \
        f32x2 zi = {za[0], zb[0]}, zf = {za[1], zb[1]};                      \
        f32x2 zg = {za[2], zb[2]}, zo = {za[3], zb[3]};                      \
        f32x2 h2 = lstm_pair(zi, zf, zg, zo, &cst);                          \
        u32 p = pack_bf16(h2.x, h2.y);                                       \
        *(u32*)&hbuf[WB][cn & 7][wcol] = p;                                  \
        *(u32*)hop = p;                                                      \
        hop += hdelta;                                                       \
        asm volatile("s_waitcnt lgkmcnt(0)\n\ts_barrier" ::: "memory");      \
    } while (0)

    for (int it = 0; it < 256; ++it) {
        LSTM_STEP(0, 1, xA, pa);
        LSTM_STEP(1, 0, xB, pb);
    }
#undef LSTM_STEP
}

// ---------------------------------------------------------------------------
// K3: feats[s,b,t] = [hf|hb] . w_out[t] + b_out[t].   block handles 32 pos.
// Paired reads (u32 for bf16 pairs, float2 for weights) halve LDS insts.
// ---------------------------------------------------------------------------
__global__ __launch_bounds__(256) void k_feats(
    const u16* __restrict__ hf, const u16* __restrict__ hb,
    const float* __restrict__ wout, const float* __restrict__ bout,
    float* __restrict__ feats)
{
    __shared__ u16 sf[32][136], sb[32][136];
    __shared__ float wo[7][260];
    __shared__ float bo[8];
    int tid = threadIdx.x;
    int pos0 = blockIdx.x * 32;
    {
        int r = tid >> 3, cc = (tid & 7) * 16;
        const uint4* pf = (const uint4*)(hf + (size_t)(pos0 + r) * 128 + cc);
        const uint4* pb = (const uint4*)(hb + (size_t)(pos0 + r) * 128 + cc);
        *(uint4*)&sf[r][cc]     = pf[0];
        *(uint4*)&sf[r][cc + 8] = pf[1];
        *(uint4*)&sb[r][cc]     = pb[0];
        *(uint4*)&sb[r][cc + 8] = pb[1];
    }
    for (int i = tid; i < 1792; i += 256) wo[i >> 8][i & 255] = wout[i];
    if (tid < 7) bo[tid] = bout[tid];
    __syncthreads();
    int pp = tid >> 3, tt = tid & 7;
    if (tt < 7) {
        float acc = bo[tt];
        #pragma unroll 4
        for (int ch = 0; ch < 128; ch += 2) {
            u32 uf = *(const u32*)&sf[pp][ch];
            u32 ub = *(const u32*)&sb[pp][ch];
            float2 w0 = *(const float2*)&wo[tt][ch];
            float2 w1 = *(const float2*)&wo[tt][128 + ch];
            acc += __uint_as_float(uf << 16) * w0.x
                 + __uint_as_float(uf & 0xFFFF0000u) * w0.y
                 + __uint_as_float(ub << 16) * w1.x
                 + __uint_as_float(ub & 0xFFFF0000u) * w1.y;
        }
        feats[(size_t)(pos0 + pp) * 7 + tt] = acc;
    }
}

// ---------------------------------------------------------------------------
// K4a: CRF chunk fold.  block=(b, chunk of 64 steps), 512 single-wave blocks.
// M in registers (lane (i,j) holds M[i][j]); row access via __shfl.
// ---------------------------------------------------------------------------
__global__ __launch_bounds__(64) void k_crf_chunk(
    const float* __restrict__ feats, const float* __restrict__ trans,
    float* __restrict__ chunkM)
{
    int b = blockIdx.x >> 3, c = blockIdx.x & 7;
    int lane = threadIdx.x;
    int i = lane >> 3, j = lane & 7;
    __shared__ float fl[64][8];
    int s0 = c * 64;
    for (int idx = lane; idx < 448; idx += 64) {
        int ss = idx / 7, jj = idx - ss * 7;
        fl[ss][jj] = feats[(size_t)((s0 + ss) * 64 + b) * 7 + jj];
    }
    float tc[7];
    #pragma unroll
    for (int k = 0; k < 7; ++k) tc[k] = (j < 7) ? trans[k * 7 + j] : 0.f;
    bool valid = (i < 7 && j < 7);
    float M0 = valid ? trans[i * 7 + j] : -1e30f;
    __syncthreads();
    float M = M0 + (valid ? fl[0][j] : 0.f);
    for (int ss = 1; ss < 64; ++ss) {
        int rb = i * 8;
        float v0 = __shfl(M, rb + 0, 64) + tc[0];
        float v1 = __shfl(M, rb + 1, 64) + tc[1];
        float v2 = __shfl(M, rb + 2, 64) + tc[2];
        float v3 = __shfl(M, rb + 3, 64) + tc[3];
        float v4 = __shfl(M, rb + 4, 64) + tc[4];
        float v5 = __shfl(M, rb + 5, 64) + tc[5];
        float v6 = __shfl(M, rb + 6, 64) + tc[6];
        float mx = fmaxf(fmaxf(fmaxf(v0, v1), fmaxf(v2, v3)),
                         fmaxf(fmaxf(v4, v5), v6));
        float sm = __expf(v0 - mx) + __expf(v1 - mx) + __expf(v2 - mx)
                 + __expf(v3 - mx) + __expf(v4 - mx) + __expf(v5 - mx)
                 + __expf(v6 - mx);
        M = mx + __logf(sm) + fl[ss][j];
    }
    if (valid)
        chunkM[(size_t)(b * 8 + c) * 49 + i * 7 + j] = M;
}

// ---------------------------------------------------------------------------
// K4b: SINGLE-block final fold.  8 waves x 8 batches; lane = k*8+j
// handles (batch w*8+k, tag j).  Folds 8 chunk matrices via shuffle-lse,
// adds STOP row, computes gold with all 512 threads, block-reduces, and
// writes d_out[0] with a plain store.
// ---------------------------------------------------------------------------
__global__ __launch_bounds__(512) void k_crf_final(
    const float* __restrict__ chunkM, const float* __restrict__ trans,
    const int* __restrict__ tags, const float* __restrict__ feats,
    float* __restrict__ out)
{
    int tid = threadIdx.x;
    int w = tid >> 6, lane = tid & 63;
    int k = lane >> 3, j = lane & 7;
    int b = w * 8 + k;
    bool jv = (j < 7);
    __shared__ float Tl[49];
    __shared__ float red[512];
    __shared__ float fsh[64];
    if (tid < 49) Tl[tid] = trans[tid];
    __syncthreads();

    float av = (j == 5) ? 0.f : -1e4f;          // alpha0
    #pragma unroll
    for (int c = 0; c < 8; ++c) {
        float a0 = __shfl(av, k * 8 + 0, 64);
        float a1 = __shfl(av, k * 8 + 1, 64);
        float a2 = __shfl(av, k * 8 + 2, 64);
        float a3 = __shfl(av, k * 8 + 3, 64);
        float a4 = __shfl(av, k * 8 + 4, 64);
        float a5 = __shfl(av, k * 8 + 5, 64);
        float a6 = __shfl(av, k * 8 + 6, 64);
        if (jv) {
            const float* Pp = chunkM + ((size_t)b * 8 + c) * 49 + j;
            float v0 = a0 + Pp[0],  v1 = a1 + Pp[7],  v2 = a2 + Pp[14];
            float v3 = a3 + Pp[21], v4 = a4 + Pp[28], v5 = a5 + Pp[35];
            float v6 = a6 + Pp[42];
            float mx = fmaxf(fmaxf(fmaxf(v0, v1), fmaxf(v2, v3)),
                             fmaxf(fmaxf(v4, v5), v6));
            float sm = __expf(v0 - mx) + __expf(v1 - mx) + __expf(v2 - mx)
                     + __expf(v3 - mx) + __expf(v4 - mx) + __expf(v5 - mx)
                     + __expf(v6 - mx);
            av = mx + __logf(sm);
        }
    }
    // fwd = lse_j(av[j] + trans[STOP=6][j]) over the 8-lane j-group
    float u = jv ? (av + Tl[42 + j]) : -1e30f;
    float m = u;
    #pragma unroll
    for (int off = 1; off < 8; off <<= 1) m = fmaxf(m, __shfl_xor(m, off, 64));
    float e = jv ? __expf(u - m) : 0.f;
    #pragma unroll
    for (int off = 1; off < 8; off <<= 1) e += __shfl_xor(e, off, 64);
    float fwd = m + __logf(e);
    if (j == 0) fsh[b] = fwd;

    // gold: thread handles batch tb, quarter q (64 steps each)
    int tb = tid & 63, q = tid >> 6;
    const int* tgp = tags + (size_t)tb * 512;
    float acc = 0.f;
    int tp = (q == 0) ? 5 : tgp[q * 64 - 1];
    for (int ss = q * 64; ss < q * 64 + 64; ++ss) {
        int tn = tgp[ss];
        acc += Tl[tn * 7 + tp] + feats[(size_t)(ss * 64 + tb) * 7 + tn];
        tp = tn;
    }
    if (q == 7) acc += Tl[42 + tgp[511]];
    red[tid] = acc;
    __syncthreads();
    if (tid < 64) {
        float g = red[tid];
        #pragma unroll
        for (int qq = 1; qq < 8; ++qq) g += red[tid + 64 * qq];
        red[tid] = fsh[tid] - g;
    }
    __syncthreads();
    if (tid < 64) {
        float v = red[tid];
        #pragma unroll
        for (int off = 1; off < 64; off <<= 1) v += __shfl_xor(v, off, 64);
        if (tid == 0) out[0] = v * (1.0f / 64.0f);
    }
}

// ---------------------------------------------------------------------------
extern "C" void kernel_launch(void* const* d_in, const int* in_sizes, int n_in,
                              void* d_out, int out_size, void* d_ws, size_t ws_size,
                              hipStream_t stream) {
    const int*   sent = (const int*)d_in[0];
    const int*   tags = (const int*)d_in[1];
    const float* h0   = (const float*)d_in[2];
    const float* c0   = (const float*)d_in[3];
    const float* emb  = (const float*)d_in[4];
    const float* wihf = (const float*)d_in[5];
    const float* whhf = (const float*)d_in[6];
    const float* bihf = (const float*)d_in[7];
    const float* bhhf = (const float*)d_in[8];
    const float* wihb = (const float*)d_in[9];
    const float* whhb = (const float*)d_in[10];
    const float* bihb = (const float*)d_in[11];
    const float* bhhb = (const float*)d_in[12];
    const float* wout = (const float*)d_in[13];
    const float* bout = (const float*)d_in[14];
    const float* trn  = (const float*)d_in[15];

    char* ws = (char*)d_ws;
    u16*   Xf     = (u16*)(ws);                       // 33,554,432 B
    u16*   Xb     = (u16*)(ws + 33554432);            // 33,554,432 B
    u16*   hfp    = (u16*)(ws + 67108864);            //  8,388,608 B
    u16*   hbp    = (u16*)(ws + 75497472);            //  8,388,608 B
    float* feats  = (float*)(ws + 83886080);          //    917,504 B
    float* chunkM = (float*)(ws + 84803584);          //    100,352 B

    k_inproj2<<<256, 512, 0, stream>>>(sent, emb, wihf, bihf, bhhf,
                                       wihb, bihb, bhhb, Xf, Xb);
    k_lstm<<<16, 512, 0, stream>>>(h0, c0, whhf, whhb, Xf, Xb, hfp, hbp);
    k_feats<<<1024, 256, 0, stream>>>(hfp, hbp, wout, bout, feats);
    k_crf_chunk<<<512, 64, 0, stream>>>(feats, trn, chunkM);
    k_crf_final<<<1, 512, 0, stream>>>(chunkM, trn, tags, feats, (float*)d_out);
}